// Round 4
// baseline (2274.930 us; speedup 1.0000x reference)
//
#include <hip/hip_runtime.h>
#include <stdint.h>

#define NTOK 8192
#define H_ 1024
#define F_ 4096
#define E_ 8
#define VCAP 18432      // 16384 slots + up to 8*256 padding (virtual rows)
#define VMBLK 72        // VCAP/256
#define NCOMP 16384     // compact rows (= NTOK * k exactly)

using f32x4  = __attribute__((ext_vector_type(4))) float;
using short8 = __attribute__((ext_vector_type(8))) short;

typedef __attribute__((address_space(1))) const uint32_t gu32;
typedef __attribute__((address_space(3))) uint32_t lu32;

__device__ __forceinline__ void glds16(const void* g, void* l) {
  __builtin_amdgcn_global_load_lds((gu32*)g, (lu32*)l, 16, 0, 0);
}

__device__ __forceinline__ ushort f2bf(float f) {
  union { float f; uint32_t u; } v; v.f = f;
  uint32_t r = (v.u + 0x7FFFu + ((v.u >> 16) & 1u)) >> 16;
  return (ushort)r;
}

__device__ __forceinline__ float gelu_t(float x) {
  // tanh-form gelu; |err| vs exact erf-gelu <= ~3e-3 (fits bf16-scale threshold)
  float u = 0.7978845608028654f * (x + 0.044715f * x * x * x);
  float e = exp2f(u * 2.885390081777927f);      // exp(2u)
  float th = 1.0f - 2.0f / (1.0f + e);
  return 0.5f * x * (1.0f + th);
}

// ---------------- init ------------------------------------------------------
__global__ void k_init(int* cnt, int* cur, int* tok, float* wl, int* v2c) {
  int i = blockIdx.x * 256 + threadIdx.x;
  if (i < E_) { cnt[i] = 0; cur[i] = 0; }
  if (i < VCAP) { tok[i] = -1; wl[i] = 0.f; v2c[i] = -1; }
}

// ---------------- transpose + fp32->bf16: W[E][R][C] -> WT[E][C][R] ---------
__global__ __launch_bounds__(256) void k_transcvt(const float* __restrict__ W,
                                                  ushort* __restrict__ WT,
                                                  int R, int C) {
  __shared__ float t[64][65];
  int e = blockIdx.z;
  int c0 = blockIdx.x * 64, r0 = blockIdx.y * 64;
  const float* Wp = W + (size_t)e * R * C;
  ushort* Tp = WT + (size_t)e * R * C;
  int tx = threadIdx.x & 15, ty = threadIdx.x >> 4;
#pragma unroll
  for (int i = 0; i < 4; i++) {
    int lr = ty + i * 16;
    const float4 v = *(const float4*)&Wp[(size_t)(r0 + lr) * C + c0 + tx * 4];
    t[lr][tx * 4 + 0] = v.x; t[lr][tx * 4 + 1] = v.y;
    t[lr][tx * 4 + 2] = v.z; t[lr][tx * 4 + 3] = v.w;
  }
  __syncthreads();
#pragma unroll
  for (int i = 0; i < 4; i++) {
    int lc = ty + i * 16;
    ushort4 o;
    o.x = f2bf(t[tx * 4 + 0][lc]);
    o.y = f2bf(t[tx * 4 + 1][lc]);
    o.z = f2bf(t[tx * 4 + 2][lc]);
    o.w = f2bf(t[tx * 4 + 3][lc]);
    *(ushort4*)&Tp[(size_t)(c0 + lc) * R + r0 + tx * 4] = o;
  }
}

// ---------------- router ----------------------------------------------------
__global__ __launch_bounds__(256) void k_router(const float* __restrict__ x,
                                                const float* __restrict__ Wr,
                                                const float* __restrict__ br,
                                                const float* __restrict__ bbuf,
                                                int* cnt, int* te, float* tw) {
  int wid = threadIdx.x >> 6, lane = threadIdx.x & 63;
  int t = blockIdx.x * 4 + wid;
  const float* xp = x + (size_t)t * H_;
  double acc[E_];
#pragma unroll
  for (int e = 0; e < E_; e++) acc[e] = 0.0;
  for (int j = lane; j < H_; j += 64) {
    float xv = xp[j];
    const float4 w0 = *(const float4*)&Wr[j * 8];
    const float4 w1 = *(const float4*)&Wr[j * 8 + 4];
    acc[0] += (double)xv * (double)w0.x;
    acc[1] += (double)xv * (double)w0.y;
    acc[2] += (double)xv * (double)w0.z;
    acc[3] += (double)xv * (double)w0.w;
    acc[4] += (double)xv * (double)w1.x;
    acc[5] += (double)xv * (double)w1.y;
    acc[6] += (double)xv * (double)w1.z;
    acc[7] += (double)xv * (double)w1.w;
  }
#pragma unroll
  for (int e = 0; e < E_; e++)
    for (int s = 32; s > 0; s >>= 1) acc[e] += __shfl_xor(acc[e], s);
  if (lane == 0) {
    double s[E_], m = -1e300;
    for (int e = 0; e < E_; e++) { s[e] = acc[e] + (double)br[e]; if (s[e] > m) m = s[e]; }
    double pe[E_], sum = 0.0;
    for (int e = 0; e < E_; e++) { pe[e] = exp(s[e] - m); sum += pe[e]; }
    double pr[E_], bb[E_];
    for (int e = 0; e < E_; e++) { pr[e] = pe[e] / sum; bb[e] = pr[e] + (double)bbuf[e]; }
    int e0 = 0;
    for (int e = 1; e < E_; e++) if (bb[e] > bb[e0]) e0 = e;
    int e1 = (e0 == 0) ? 1 : 0;
    for (int e = 0; e < E_; e++) if (e != e0 && bb[e] > bb[e1]) e1 = e;
    int a0 = 0;
    for (int e = 1; e < E_; e++) if (pr[e] > pr[a0]) a0 = e;
    int a1 = (a0 == 0) ? 1 : 0;
    for (int e = 0; e < E_; e++) if (e != a0 && pr[e] > pr[a1]) a1 = e;
    double iv = 1.0 / (pr[a0] + pr[a1]);
    te[t * 2] = e0; te[t * 2 + 1] = e1;
    tw[t * 2] = (float)(pr[a0] * iv); tw[t * 2 + 1] = (float)(pr[a1] * iv);
    atomicAdd(&cnt[e0], 1); atomicAdd(&cnt[e1], 1);
  }
}

// ---------------- offsets: 256-padded virtual + compact prefix --------------
__global__ void k_offsets(const int* cnt, int* off, int* coff) {
  if (threadIdx.x == 0 && blockIdx.x == 0) {
    int o = 0, c = 0;
    for (int e = 0; e < E_; e++) {
      off[e] = o; coff[e] = c;
      o += ((cnt[e] + 255) >> 8) << 8;
      c += cnt[e];
    }
    off[E_] = o; coff[E_] = c;
  }
}

// ---------------- build token lists -----------------------------------------
__global__ void k_build(const int* __restrict__ te, const float* __restrict__ tw,
                        const int* __restrict__ off, const int* __restrict__ coff,
                        int* cur, int* tok, float* wl, int* v2c, int* ctok) {
  int t = blockIdx.x * 256 + threadIdx.x;
  if (t >= NTOK) return;
#pragma unroll
  for (int s = 0; s < 2; s++) {
    int e = te[t * 2 + s];
    int slot = atomicAdd(&cur[e], 1);
    int vp = off[e] + slot;
    int cp = coff[e] + slot;
    tok[vp] = t; wl[vp] = tw[t * 2 + s]; v2c[vp] = cp; ctok[cp] = t;
  }
}

// ---------------- gather x rows -> bf16 compact ------------------------------
__global__ __launch_bounds__(256) void k_gather(const float* __restrict__ x,
                                                const int* __restrict__ ctok,
                                                ushort* __restrict__ Xg) {
  int row = blockIdx.x;
  int t = ctok[row];
  const float4* src = (const float4*)(x + (size_t)t * H_);
  ushort4* dst = (ushort4*)(Xg + (size_t)row * H_);
  int i = threadIdx.x;
  float4 v = src[i];
  ushort4 o; o.x = f2bf(v.x); o.y = f2bf(v.y); o.z = f2bf(v.z); o.w = f2bf(v.w);
  dst[i] = o;
}

// ---------------- zero output ------------------------------------------------
__global__ void k_zero(float* out) {
  size_t i = (size_t)blockIdx.x * 256 + threadIdx.x;
  float4 z; z.x = 0.f; z.y = 0.f; z.z = 0.f; z.w = 0.f;
  ((float4*)out)[i] = z;
}

// ---------------- 256x256x64 MFMA GEMM, K-half-phased counted pipeline ------
// A [compact rows][K] bf16 (indirected via v2c); BT [E][N][K] bf16.
// LDS per buffer (64KB): A [ks][256 rows][32 k-elems], B [ks][256 cols][32].
// Swizzle: LDS[row][chunk c] holds global chunk c ^ g(row), g(r)=(r&3)^((r>>2)&3).
// Pipeline: per K=32 half-phase: stage(t+1,ks) -> 12 ds_read -> 32 MFMA ->
// vmcnt(4) + barrier. Always 4 loads in flight; never drains mid-loop.
// MODE 0: h1[v2c[row]] = gelu(A@B + b1[e]).  MODE 1: atomicAdd into Out.
template <int MODE>
__global__ __launch_bounds__(512, 2) void k_gemm(const ushort* __restrict__ A,
                                                 const ushort* __restrict__ BT,
                                                 const float* __restrict__ bias,
                                                 ushort* __restrict__ h1,
                                                 float* __restrict__ Out,
                                                 const int* __restrict__ off,
                                                 const int* __restrict__ v2c,
                                                 const int* __restrict__ tok,
                                                 const float* __restrict__ wl,
                                                 int K, int N, int NTe) {
  extern __shared__ char lds[];
  // ---- raster: XCD chunk, group-of-4 M, N fastest ----
  int nwg = gridDim.x;             // divisible by 8
  int cpx = nwg >> 3;
  int bid = blockIdx.x;
  int lid = (bid & 7) * cpx + (bid >> 3);
  int gsz = NTe << 2;
  int g = lid / gsz, r = lid % gsz;
  int ne = r >> 2, m = (g << 2) + (r & 3);
  int row0 = m << 8;
  if (row0 >= off[E_]) return;
  int e = 0;
  while (off[e + 1] <= row0) e++;
  int n0, k0, nk;
  if (MODE == 0) { n0 = ne << 8; k0 = 0; nk = K >> 6; }
  else           { n0 = (ne >> 1) << 8; k0 = (ne & 1) * (K >> 1); nk = K >> 7; }
  const ushort* Bp = BT + (size_t)e * (size_t)N * (size_t)K;

  int tid = threadIdx.x, lane = tid & 63, w = tid >> 6;
  int wr = w >> 2, wc = w & 3;

  f32x4 acc[8][4];
#pragma unroll
  for (int mm = 0; mm < 8; mm++)
#pragma unroll
    for (int nn = 0; nn < 4; nn++) acc[mm][nn] = (f32x4){0.f, 0.f, 0.f, 0.f};

  // ---- staging addressing ----
  int ur = lane >> 2;                         // row within 16-row unit
  int uc = lane & 3;                          // lds chunk this lane fills
  int gr = (ur & 3) ^ ((ur >> 2) & 3);        // swizzle of row
  int sc = uc ^ gr;                           // pre-swizzled source chunk
  int vr0 = row0 + (w << 4) + ur;
  int cr0 = v2c[vr0];       if (cr0 < 0) cr0 = 0;
  int cr1 = v2c[vr0 + 128]; if (cr1 < 0) cr1 = 0;
  const char* aP0 = (const char*)(A + (size_t)cr0 * K) + k0 * 2 + sc * 16;
  const char* aP1 = (const char*)(A + (size_t)cr1 * K) + k0 * 2 + sc * 16;
  const char* bP0 = (const char*)(Bp + (size_t)(n0 + (w << 4) + ur) * K) + k0 * 2 + sc * 16;
  const char* bP1 = (const char*)(Bp + (size_t)(n0 + 128 + (w << 4) + ur) * K) + k0 * 2 + sc * 16;

  // ---- fragment read addressing ----
  int fr = lane & 15, fq = lane >> 4;
  int sg = (fr & 3) ^ ((fr >> 2) & 3);
  int kchunk = (fq ^ sg) << 3;                // ushort offset within row

#define STAGE(tt, kss, bb) do {                                        \
    size_t kb = (size_t)(tt) * 128 + (size_t)(kss) * 64;               \
    char* db = lds + (bb) * 65536 + (kss) * 16384;                     \
    glds16(aP0 + kb, db + (w << 10));                                  \
    glds16(aP1 + kb, db + ((w + 8) << 10));                            \
    glds16(bP0 + kb, db + 32768 + (w << 10));                          \
    glds16(bP1 + kb, db + 32768 + ((w + 8) << 10));                    \
  } while (0)

#define COMPUTE(bb, kss) do {                                          \
    const ushort* LA = (const ushort*)(lds + (bb) * 65536 + (kss) * 16384); \
    const ushort* LB = LA + 16384;                                     \
    short8 af[8], bfm[4];                                              \
    _Pragma("unroll")                                                  \
    for (int mm = 0; mm < 8; mm++)                                     \
      af[mm] = *(const short8*)&LA[((wr << 7) + mm * 16 + fr) * 32 + kchunk]; \
    _Pragma("unroll")                                                  \
    for (int nn = 0; nn < 4; nn++)                                     \
      bfm[nn] = *(const short8*)&LB[((wc << 6) + nn * 16 + fr) * 32 + kchunk]; \
    __builtin_amdgcn_s_setprio(1);                                     \
    _Pragma("unroll")                                                  \
    for (int mm = 0; mm < 8; mm++)                                     \
      _Pragma("unroll")                                                \
      for (int nn = 0; nn < 4; nn++)                                   \
        acc[mm][nn] = __builtin_amdgcn_mfma_f32_16x16x32_bf16(af[mm], bfm[nn], acc[mm][nn], 0, 0, 0); \
    __builtin_amdgcn_s_setprio(0);                                     \
  } while (0)

  // prologue: stage tile 0 (both K-halves) into buf 0
  STAGE(0, 0, 0);
  STAGE(0, 1, 0);
  asm volatile("s_waitcnt vmcnt(4)" ::: "memory");   // (0,ks0) landed
  __builtin_amdgcn_s_barrier();
  __builtin_amdgcn_sched_barrier(0);

  for (int t = 0; t < nk; t++) {
    int bb = t & 1;
    // ---- half-phase ks=0 ----
    if (t + 1 < nk) STAGE(t + 1, 0, bb ^ 1);
    COMPUTE(bb, 0);
    if (t + 1 < nk) asm volatile("s_waitcnt vmcnt(4)" ::: "memory");  // (t,ks1) landed
    else            asm volatile("s_waitcnt vmcnt(0)" ::: "memory");
    __builtin_amdgcn_s_barrier();
    __builtin_amdgcn_sched_barrier(0);
    // ---- half-phase ks=1 ----
    if (t + 1 < nk) {
      STAGE(t + 1, 1, bb ^ 1);
      COMPUTE(bb, 1);
      asm volatile("s_waitcnt vmcnt(4)" ::: "memory");                // (t+1,ks0) landed
      __builtin_amdgcn_s_barrier();
      __builtin_amdgcn_sched_barrier(0);
    } else {
      COMPUTE(bb, 1);
    }
  }
#undef STAGE
#undef COMPUTE

  // ---- epilogue ----
  const float* bp = bias + (size_t)e * N;
  int cbase = n0 + (wc << 6);
  if (MODE == 0) {
#pragma unroll
    for (int mm = 0; mm < 8; mm++) {
#pragma unroll
      for (int j = 0; j < 4; j++) {
        int vr = row0 + (wr << 7) + mm * 16 + (fq << 2) + j;
        int cr = v2c[vr];
        if (cr < 0) continue;
        ushort* hp = h1 + (size_t)cr * N + cbase;
#pragma unroll
        for (int nn = 0; nn < 4; nn++) {
          float v = acc[mm][nn][j] + bp[cbase + nn * 16 + fr];
          hp[nn * 16 + fr] = f2bf(gelu_t(v));
        }
      }
    }
  } else {
    bool addb = (k0 == 0);
#pragma unroll
    for (int mm = 0; mm < 8; mm++) {
#pragma unroll
      for (int j = 0; j < 4; j++) {
        int vr = row0 + (wr << 7) + mm * 16 + (fq << 2) + j;
        int t2 = tok[vr];
        if (t2 < 0) continue;
        float wgt = wl[vr];
#pragma unroll
        for (int nn = 0; nn < 4; nn++) {
          int c = cbase + nn * 16 + fr;
          float v = acc[mm][nn][j] + (addb ? bp[c] : 0.f);
          atomicAdd(&Out[(size_t)t2 * (size_t)N + c], wgt * v);
        }
      }
    }
  }
}

extern "C" void kernel_launch(void* const* d_in, const int* in_sizes, int n_in,
                              void* d_out, int out_size, void* d_ws, size_t ws_size,
                              hipStream_t stream) {
  (void)in_sizes; (void)n_in; (void)out_size; (void)ws_size;
  const float* x    = (const float*)d_in[0];
  const float* bbuf = (const float*)d_in[1];
  const float* Wr   = (const float*)d_in[2];
  const float* br   = (const float*)d_in[3];
  const float* W1   = (const float*)d_in[4];
  const float* b1   = (const float*)d_in[5];
  const float* W2   = (const float*)d_in[6];
  const float* b2   = (const float*)d_in[7];
  float* out = (float*)d_out;

  char* ws = (char*)d_ws;
  ushort* W1T = (ushort*)ws;                          // [E][F][H] bf16  64 MB
  ushort* W2T = (ushort*)(ws + 67108864);             // [E][H][F] bf16  64 MB
  ushort* Xg  = (ushort*)(ws + 134217728);            // [NCOMP][H] bf16 32 MB
  ushort* h1  = (ushort*)(ws + 167772160);            // [NCOMP][F] bf16 128 MB
  char* meta  = ws + 301989888;
  int*   cnt  = (int*)(meta);
  int*   off  = (int*)(meta + 64);
  int*   coff = (int*)(meta + 128);
  int*   cur  = (int*)(meta + 192);
  int*   te   = (int*)(meta + 256);                   // [NTOK*2]
  float* tw   = (float*)(meta + 65792);               // [NTOK*2]
  int*   tok  = (int*)(meta + 131328);                // [VCAP]
  float* wl   = (float*)(meta + 205056);              // [VCAP]
  int*   v2c  = (int*)(meta + 278784);                // [VCAP]
  int*   ctok = (int*)(meta + 352512);                // [NCOMP]

  hipFuncSetAttribute((const void*)&k_gemm<0>,
                      hipFuncAttributeMaxDynamicSharedMemorySize, 131072);
  hipFuncSetAttribute((const void*)&k_gemm<1>,
                      hipFuncAttributeMaxDynamicSharedMemorySize, 131072);

  k_init<<<VMBLK, 256, 0, stream>>>(cnt, cur, tok, wl, v2c);
  k_transcvt<<<dim3(F_ / 64, H_ / 64, E_), 256, 0, stream>>>(W1, W1T, H_, F_);
  k_transcvt<<<dim3(H_ / 64, F_ / 64, E_), 256, 0, stream>>>(W2, W2T, F_, H_);
  k_router<<<NTOK / 4, 256, 0, stream>>>(x, Wr, br, bbuf, cnt, te, tw);
  k_offsets<<<1, 64, 0, stream>>>(cnt, off, coff);
  k_build<<<NTOK / 256, 256, 0, stream>>>(te, tw, off, coff, cur, tok, wl, v2c, ctok);
  k_gather<<<NCOMP, 256, 0, stream>>>(x, ctok, Xg);
  k_zero<<<(NTOK * H_ / 4) / 256, 256, 0, stream>>>(out);
  // GEMM1: M=VCAP virtual, N=4096, K=1024. 16 N-tiles x 72 M-tiles = 1152 blocks
  k_gemm<0><<<16 * VMBLK, 512, 131072, stream>>>(Xg, W1T, b1, h1, nullptr,
                                                 off, v2c, nullptr, nullptr,
                                                 H_, F_, 16);
  // GEMM2: N=1024, K=4096 split 2. (4 n-tiles x 2 splits) x 72 = 576 blocks
  k_gemm<1><<<8 * VMBLK, 512, 131072, stream>>>(h1, W2T, b2, nullptr, out,
                                                off, v2c, tok, wl,
                                                F_, H_, 8);
}

// Round 5
// 2272.026 us; speedup vs baseline: 1.0013x; 1.0013x over previous
//
#include <hip/hip_runtime.h>
#include <stdint.h>

#define NTOK 8192
#define H_ 1024
#define F_ 4096
#define E_ 8
#define VCAP 18432      // 16384 slots + up to 8*256 padding (virtual rows)
#define VMBLK 72        // VCAP/256
#define NCOMP 16384     // compact rows (= NTOK * k exactly)

using f32x4  = __attribute__((ext_vector_type(4))) float;
using short8 = __attribute__((ext_vector_type(8))) short;

typedef __attribute__((address_space(1))) const uint32_t gu32;
typedef __attribute__((address_space(3))) uint32_t lu32;

__device__ __forceinline__ void glds16(const void* g, void* l) {
  __builtin_amdgcn_global_load_lds((gu32*)g, (lu32*)l, 16, 0, 0);
}

__device__ __forceinline__ ushort f2bf(float f) {
  union { float f; uint32_t u; } v; v.f = f;
  uint32_t r = (v.u + 0x7FFFu + ((v.u >> 16) & 1u)) >> 16;
  return (ushort)r;
}

__device__ __forceinline__ float gelu_t(float x) {
  // tanh-form gelu; |err| vs exact erf-gelu <= ~3e-3 (fits bf16-scale threshold)
  float u = 0.7978845608028654f * (x + 0.044715f * x * x * x);
  float e = exp2f(u * 2.885390081777927f);      // exp(2u)
  float th = 1.0f - 2.0f / (1.0f + e);
  return 0.5f * x * (1.0f + th);
}

// ---------------- init ------------------------------------------------------
__global__ void k_init(int* cnt, int* cur, int* tok, float* wl, int* v2c) {
  int i = blockIdx.x * 256 + threadIdx.x;
  if (i < E_) { cnt[i] = 0; cur[i] = 0; }
  if (i < VCAP) { tok[i] = -1; wl[i] = 0.f; v2c[i] = -1; }
}

// ---------------- transpose + fp32->bf16: W[E][R][C] -> WT[E][C][R] ---------
__global__ __launch_bounds__(256) void k_transcvt(const float* __restrict__ W,
                                                  ushort* __restrict__ WT,
                                                  int R, int C) {
  __shared__ float t[64][65];
  int e = blockIdx.z;
  int c0 = blockIdx.x * 64, r0 = blockIdx.y * 64;
  const float* Wp = W + (size_t)e * R * C;
  ushort* Tp = WT + (size_t)e * R * C;
  int tx = threadIdx.x & 15, ty = threadIdx.x >> 4;
#pragma unroll
  for (int i = 0; i < 4; i++) {
    int lr = ty + i * 16;
    const float4 v = *(const float4*)&Wp[(size_t)(r0 + lr) * C + c0 + tx * 4];
    t[lr][tx * 4 + 0] = v.x; t[lr][tx * 4 + 1] = v.y;
    t[lr][tx * 4 + 2] = v.z; t[lr][tx * 4 + 3] = v.w;
  }
  __syncthreads();
#pragma unroll
  for (int i = 0; i < 4; i++) {
    int lc = ty + i * 16;
    ushort4 o;
    o.x = f2bf(t[tx * 4 + 0][lc]);
    o.y = f2bf(t[tx * 4 + 1][lc]);
    o.z = f2bf(t[tx * 4 + 2][lc]);
    o.w = f2bf(t[tx * 4 + 3][lc]);
    *(ushort4*)&Tp[(size_t)(c0 + lc) * R + r0 + tx * 4] = o;
  }
}

// ---------------- router ----------------------------------------------------
__global__ __launch_bounds__(256) void k_router(const float* __restrict__ x,
                                                const float* __restrict__ Wr,
                                                const float* __restrict__ br,
                                                const float* __restrict__ bbuf,
                                                int* cnt, int* te, float* tw) {
  int wid = threadIdx.x >> 6, lane = threadIdx.x & 63;
  int t = blockIdx.x * 4 + wid;
  const float* xp = x + (size_t)t * H_;
  double acc[E_];
#pragma unroll
  for (int e = 0; e < E_; e++) acc[e] = 0.0;
  for (int j = lane; j < H_; j += 64) {
    float xv = xp[j];
    const float4 w0 = *(const float4*)&Wr[j * 8];
    const float4 w1 = *(const float4*)&Wr[j * 8 + 4];
    acc[0] += (double)xv * (double)w0.x;
    acc[1] += (double)xv * (double)w0.y;
    acc[2] += (double)xv * (double)w0.z;
    acc[3] += (double)xv * (double)w0.w;
    acc[4] += (double)xv * (double)w1.x;
    acc[5] += (double)xv * (double)w1.y;
    acc[6] += (double)xv * (double)w1.z;
    acc[7] += (double)xv * (double)w1.w;
  }
#pragma unroll
  for (int e = 0; e < E_; e++)
    for (int s = 32; s > 0; s >>= 1) acc[e] += __shfl_xor(acc[e], s);
  if (lane == 0) {
    double s[E_], m = -1e300;
    for (int e = 0; e < E_; e++) { s[e] = acc[e] + (double)br[e]; if (s[e] > m) m = s[e]; }
    double pe[E_], sum = 0.0;
    for (int e = 0; e < E_; e++) { pe[e] = exp(s[e] - m); sum += pe[e]; }
    double pr[E_], bb[E_];
    for (int e = 0; e < E_; e++) { pr[e] = pe[e] / sum; bb[e] = pr[e] + (double)bbuf[e]; }
    int e0 = 0;
    for (int e = 1; e < E_; e++) if (bb[e] > bb[e0]) e0 = e;
    int e1 = (e0 == 0) ? 1 : 0;
    for (int e = 0; e < E_; e++) if (e != e0 && bb[e] > bb[e1]) e1 = e;
    int a0 = 0;
    for (int e = 1; e < E_; e++) if (pr[e] > pr[a0]) a0 = e;
    int a1 = (a0 == 0) ? 1 : 0;
    for (int e = 0; e < E_; e++) if (e != a0 && pr[e] > pr[a1]) a1 = e;
    double iv = 1.0 / (pr[a0] + pr[a1]);
    te[t * 2] = e0; te[t * 2 + 1] = e1;
    tw[t * 2] = (float)(pr[a0] * iv); tw[t * 2 + 1] = (float)(pr[a1] * iv);
    atomicAdd(&cnt[e0], 1); atomicAdd(&cnt[e1], 1);
  }
}

// ---------------- offsets: 256-padded virtual + compact prefix --------------
__global__ void k_offsets(const int* cnt, int* off, int* coff) {
  if (threadIdx.x == 0 && blockIdx.x == 0) {
    int o = 0, c = 0;
    for (int e = 0; e < E_; e++) {
      off[e] = o; coff[e] = c;
      o += ((cnt[e] + 255) >> 8) << 8;
      c += cnt[e];
    }
    off[E_] = o; coff[E_] = c;
  }
}

// ---------------- build token lists -----------------------------------------
__global__ void k_build(const int* __restrict__ te, const float* __restrict__ tw,
                        const int* __restrict__ off, const int* __restrict__ coff,
                        int* cur, int* tok, float* wl, int* v2c, int* ctok) {
  int t = blockIdx.x * 256 + threadIdx.x;
  if (t >= NTOK) return;
#pragma unroll
  for (int s = 0; s < 2; s++) {
    int e = te[t * 2 + s];
    int slot = atomicAdd(&cur[e], 1);
    int vp = off[e] + slot;
    int cp = coff[e] + slot;
    tok[vp] = t; wl[vp] = tw[t * 2 + s]; v2c[vp] = cp; ctok[cp] = t;
  }
}

// ---------------- gather x rows -> bf16 compact ------------------------------
__global__ __launch_bounds__(256) void k_gather(const float* __restrict__ x,
                                                const int* __restrict__ ctok,
                                                ushort* __restrict__ Xg) {
  int row = blockIdx.x;
  int t = ctok[row];
  const float4* src = (const float4*)(x + (size_t)t * H_);
  ushort4* dst = (ushort4*)(Xg + (size_t)row * H_);
  int i = threadIdx.x;
  float4 v = src[i];
  ushort4 o; o.x = f2bf(v.x); o.y = f2bf(v.y); o.z = f2bf(v.z); o.w = f2bf(v.w);
  dst[i] = o;
}

// ---------------- zero output ------------------------------------------------
__global__ void k_zero(float* out) {
  size_t i = (size_t)blockIdx.x * 256 + threadIdx.x;
  float4 z; z.x = 0.f; z.y = 0.f; z.z = 0.f; z.w = 0.f;
  ((float4*)out)[i] = z;
}

// ---------------- 256x256x64 MFMA GEMM, K-half-phased counted pipeline ------
// A [compact rows][K] bf16 (indirected via v2c); BT [E][N][K] bf16.
// LDS per buffer (64KB): A [ks][256 rows][32 k-elems], B [ks][256 cols][32].
// Swizzle: LDS[row][chunk c] holds global chunk c ^ g(row), g(r)=(r&3)^((r>>2)&3).
// Pipeline: per K=32 half-phase: stage(t+1,ks) -> 12 ds_read -> 32 MFMA ->
// vmcnt(4) + barrier. Always 4 loads in flight; never drains mid-loop.
// NOTE: 128 KB LDS forces 1 block/CU, so launch_bounds min-waves MUST be 1
// (R4's (512,2) capped VGPR at 128 -> acc[8][4] spilled to scratch: 1.7 GB
// WRITE_SIZE, MfmaUtil 5%).
// MODE 0: h1[v2c[row]] = gelu(A@B + b1[e]).  MODE 1: atomicAdd into Out.
template <int MODE>
__global__ __launch_bounds__(512, 1) void k_gemm(const ushort* __restrict__ A,
                                                 const ushort* __restrict__ BT,
                                                 const float* __restrict__ bias,
                                                 ushort* __restrict__ h1,
                                                 float* __restrict__ Out,
                                                 const int* __restrict__ off,
                                                 const int* __restrict__ v2c,
                                                 const int* __restrict__ tok,
                                                 const float* __restrict__ wl,
                                                 int K, int N, int NTe) {
  extern __shared__ char lds[];
  // ---- raster: XCD chunk, group-of-4 M, N fastest ----
  int nwg = gridDim.x;             // divisible by 8
  int cpx = nwg >> 3;
  int bid = blockIdx.x;
  int lid = (bid & 7) * cpx + (bid >> 3);
  int gsz = NTe << 2;
  int g = lid / gsz, r = lid % gsz;
  int ne = r >> 2, m = (g << 2) + (r & 3);
  int row0 = m << 8;
  if (row0 >= off[E_]) return;
  int e = 0;
  while (off[e + 1] <= row0) e++;
  int n0, k0, nk;
  if (MODE == 0) { n0 = ne << 8; k0 = 0; nk = K >> 6; }
  else           { n0 = (ne >> 1) << 8; k0 = (ne & 1) * (K >> 1); nk = K >> 7; }
  const ushort* Bp = BT + (size_t)e * (size_t)N * (size_t)K;

  int tid = threadIdx.x, lane = tid & 63, w = tid >> 6;
  int wr = w >> 2, wc = w & 3;

  f32x4 acc[8][4];
#pragma unroll
  for (int mm = 0; mm < 8; mm++)
#pragma unroll
    for (int nn = 0; nn < 4; nn++) acc[mm][nn] = (f32x4){0.f, 0.f, 0.f, 0.f};

  // ---- staging addressing ----
  int ur = lane >> 2;                         // row within 16-row unit
  int uc = lane & 3;                          // lds chunk this lane fills
  int gr = (ur & 3) ^ ((ur >> 2) & 3);        // swizzle of row
  int sc = uc ^ gr;                           // pre-swizzled source chunk
  int vr0 = row0 + (w << 4) + ur;
  int cr0 = v2c[vr0];       if (cr0 < 0) cr0 = 0;
  int cr1 = v2c[vr0 + 128]; if (cr1 < 0) cr1 = 0;
  const char* aP0 = (const char*)(A + (size_t)cr0 * K) + k0 * 2 + sc * 16;
  const char* aP1 = (const char*)(A + (size_t)cr1 * K) + k0 * 2 + sc * 16;
  const char* bP0 = (const char*)(Bp + (size_t)(n0 + (w << 4) + ur) * K) + k0 * 2 + sc * 16;
  const char* bP1 = (const char*)(Bp + (size_t)(n0 + 128 + (w << 4) + ur) * K) + k0 * 2 + sc * 16;

  // ---- fragment read addressing ----
  int fr = lane & 15, fq = lane >> 4;
  int sg = (fr & 3) ^ ((fr >> 2) & 3);
  int kchunk = (fq ^ sg) << 3;                // ushort offset within row

#define STAGE(tt, kss, bb) do {                                        \
    size_t kb = (size_t)(tt) * 128 + (size_t)(kss) * 64;               \
    char* db = lds + (bb) * 65536 + (kss) * 16384;                     \
    glds16(aP0 + kb, db + (w << 10));                                  \
    glds16(aP1 + kb, db + ((w + 8) << 10));                            \
    glds16(bP0 + kb, db + 32768 + (w << 10));                          \
    glds16(bP1 + kb, db + 32768 + ((w + 8) << 10));                    \
  } while (0)

#define COMPUTE(bb, kss) do {                                          \
    const ushort* LA = (const ushort*)(lds + (bb) * 65536 + (kss) * 16384); \
    const ushort* LB = LA + 16384;                                     \
    short8 af[8], bfm[4];                                              \
    _Pragma("unroll")                                                  \
    for (int mm = 0; mm < 8; mm++)                                     \
      af[mm] = *(const short8*)&LA[((wr << 7) + mm * 16 + fr) * 32 + kchunk]; \
    _Pragma("unroll")                                                  \
    for (int nn = 0; nn < 4; nn++)                                     \
      bfm[nn] = *(const short8*)&LB[((wc << 6) + nn * 16 + fr) * 32 + kchunk]; \
    __builtin_amdgcn_s_setprio(1);                                     \
    _Pragma("unroll")                                                  \
    for (int mm = 0; mm < 8; mm++)                                     \
      _Pragma("unroll")                                                \
      for (int nn = 0; nn < 4; nn++)                                   \
        acc[mm][nn] = __builtin_amdgcn_mfma_f32_16x16x32_bf16(af[mm], bfm[nn], acc[mm][nn], 0, 0, 0); \
    __builtin_amdgcn_s_setprio(0);                                     \
  } while (0)

  // prologue: stage tile 0 (both K-halves) into buf 0
  STAGE(0, 0, 0);
  STAGE(0, 1, 0);
  asm volatile("s_waitcnt vmcnt(4)" ::: "memory");   // (0,ks0) landed
  __builtin_amdgcn_s_barrier();
  __builtin_amdgcn_sched_barrier(0);

  for (int t = 0; t < nk; t++) {
    int bb = t & 1;
    // ---- half-phase ks=0 ----
    if (t + 1 < nk) STAGE(t + 1, 0, bb ^ 1);
    COMPUTE(bb, 0);
    if (t + 1 < nk) asm volatile("s_waitcnt vmcnt(4)" ::: "memory");  // (t,ks1) landed
    else            asm volatile("s_waitcnt vmcnt(0)" ::: "memory");
    __builtin_amdgcn_s_barrier();
    __builtin_amdgcn_sched_barrier(0);
    // ---- half-phase ks=1 ----
    if (t + 1 < nk) {
      STAGE(t + 1, 1, bb ^ 1);
      COMPUTE(bb, 1);
      asm volatile("s_waitcnt vmcnt(4)" ::: "memory");                // (t+1,ks0) landed
      __builtin_amdgcn_s_barrier();
      __builtin_amdgcn_sched_barrier(0);
    } else {
      COMPUTE(bb, 1);
    }
  }
#undef STAGE
#undef COMPUTE

  // ---- epilogue ----
  const float* bp = bias + (size_t)e * N;
  int cbase = n0 + (wc << 6);
  if (MODE == 0) {
#pragma unroll
    for (int mm = 0; mm < 8; mm++) {
#pragma unroll
      for (int j = 0; j < 4; j++) {
        int vr = row0 + (wr << 7) + mm * 16 + (fq << 2) + j;
        int cr = v2c[vr];
        if (cr < 0) continue;
        ushort* hp = h1 + (size_t)cr * N + cbase;
#pragma unroll
        for (int nn = 0; nn < 4; nn++) {
          float v = acc[mm][nn][j] + bp[cbase + nn * 16 + fr];
          hp[nn * 16 + fr] = f2bf(gelu_t(v));
        }
      }
    }
  } else {
    bool addb = (k0 == 0);
#pragma unroll
    for (int mm = 0; mm < 8; mm++) {
#pragma unroll
      for (int j = 0; j < 4; j++) {
        int vr = row0 + (wr << 7) + mm * 16 + (fq << 2) + j;
        int t2 = tok[vr];
        if (t2 < 0) continue;
        float wgt = wl[vr];
#pragma unroll
        for (int nn = 0; nn < 4; nn++) {
          int c = cbase + nn * 16 + fr;
          float v = acc[mm][nn][j] + (addb ? bp[c] : 0.f);
          atomicAdd(&Out[(size_t)t2 * (size_t)N + c], wgt * v);
        }
      }
    }
  }
}

extern "C" void kernel_launch(void* const* d_in, const int* in_sizes, int n_in,
                              void* d_out, int out_size, void* d_ws, size_t ws_size,
                              hipStream_t stream) {
  (void)in_sizes; (void)n_in; (void)out_size; (void)ws_size;
  const float* x    = (const float*)d_in[0];
  const float* bbuf = (const float*)d_in[1];
  const float* Wr   = (const float*)d_in[2];
  const float* br   = (const float*)d_in[3];
  const float* W1   = (const float*)d_in[4];
  const float* b1   = (const float*)d_in[5];
  const float* W2   = (const float*)d_in[6];
  const float* b2   = (const float*)d_in[7];
  float* out = (float*)d_out;

  char* ws = (char*)d_ws;
  ushort* W1T = (ushort*)ws;                          // [E][F][H] bf16  64 MB
  ushort* W2T = (ushort*)(ws + 67108864);             // [E][H][F] bf16  64 MB
  ushort* Xg  = (ushort*)(ws + 134217728);            // [NCOMP][H] bf16 32 MB
  ushort* h1  = (ushort*)(ws + 167772160);            // [NCOMP][F] bf16 128 MB
  char* meta  = ws + 301989888;
  int*   cnt  = (int*)(meta);
  int*   off  = (int*)(meta + 64);
  int*   coff = (int*)(meta + 128);
  int*   cur  = (int*)(meta + 192);
  int*   te   = (int*)(meta + 256);                   // [NTOK*2]
  float* tw   = (float*)(meta + 65792);               // [NTOK*2]
  int*   tok  = (int*)(meta + 131328);                // [VCAP]
  float* wl   = (float*)(meta + 205056);               // [VCAP]
  int*   v2c  = (int*)(meta + 278784);                // [VCAP]
  int*   ctok = (int*)(meta + 352512);                // [NCOMP]

  hipFuncSetAttribute((const void*)&k_gemm<0>,
                      hipFuncAttributeMaxDynamicSharedMemorySize, 131072);
  hipFuncSetAttribute((const void*)&k_gemm<1>,
                      hipFuncAttributeMaxDynamicSharedMemorySize, 131072);

  k_init<<<VMBLK, 256, 0, stream>>>(cnt, cur, tok, wl, v2c);
  k_transcvt<<<dim3(F_ / 64, H_ / 64, E_), 256, 0, stream>>>(W1, W1T, H_, F_);
  k_transcvt<<<dim3(H_ / 64, F_ / 64, E_), 256, 0, stream>>>(W2, W2T, F_, H_);
  k_router<<<NTOK / 4, 256, 0, stream>>>(x, Wr, br, bbuf, cnt, te, tw);
  k_offsets<<<1, 64, 0, stream>>>(cnt, off, coff);
  k_build<<<NTOK / 256, 256, 0, stream>>>(te, tw, off, coff, cur, tok, wl, v2c, ctok);
  k_gather<<<NCOMP, 256, 0, stream>>>(x, ctok, Xg);
  k_zero<<<(NTOK * H_ / 4) / 256, 256, 0, stream>>>(out);
  // GEMM1: M=VCAP virtual, N=4096, K=1024. 16 N-tiles x 72 M-tiles = 1152 blocks
  k_gemm<0><<<16 * VMBLK, 512, 131072, stream>>>(Xg, W1T, b1, h1, nullptr,
                                                 off, v2c, nullptr, nullptr,
                                                 H_, F_, 16);
  // GEMM2: N=1024, K=4096 split 2. (4 n-tiles x 2 splits) x 72 = 576 blocks
  k_gemm<1><<<8 * VMBLK, 512, 131072, stream>>>(h1, W2T, b2, nullptr, out,
                                                off, v2c, tok, wl,
                                                F_, H_, 8);
}

// Round 6
// 1039.777 us; speedup vs baseline: 2.1879x; 2.1851x over previous
//
#include <hip/hip_runtime.h>
#include <stdint.h>

#define NTOK 8192
#define H_ 1024
#define F_ 4096
#define E_ 8
#define VCAP 18432      // 16384 slots + up to 8*256 padding (virtual rows)
#define VMBLK 72        // VCAP/256
#define NCOMP 16384     // compact rows (= NTOK * k exactly)

using f32x4  = __attribute__((ext_vector_type(4))) float;
using short8 = __attribute__((ext_vector_type(8))) short;

typedef __attribute__((address_space(1))) const uint32_t gu32;
typedef __attribute__((address_space(3))) uint32_t lu32;

__device__ __forceinline__ void glds16(const void* g, void* l) {
  __builtin_amdgcn_global_load_lds((gu32*)g, (lu32*)l, 16, 0, 0);
}

__device__ __forceinline__ ushort f2bf(float f) {
  union { float f; uint32_t u; } v; v.f = f;
  uint32_t r = (v.u + 0x7FFFu + ((v.u >> 16) & 1u)) >> 16;
  return (ushort)r;
}

__device__ __forceinline__ float gelu_t(float x) {
  float u = 0.7978845608028654f * (x + 0.044715f * x * x * x);
  float e = exp2f(u * 2.885390081777927f);      // exp(2u)
  float th = 1.0f - 2.0f / (1.0f + e);
  return 0.5f * x * (1.0f + th);
}

// ---------------- init ------------------------------------------------------
__global__ void k_init(int* cnt, int* cur, int* tok, float* wl, int* v2c) {
  int i = blockIdx.x * 256 + threadIdx.x;
  if (i < E_) { cnt[i] = 0; cur[i] = 0; }
  if (i < VCAP) { tok[i] = -1; wl[i] = 0.f; v2c[i] = -1; }
}

// ---------------- transpose + fp32->bf16: W[E][R][C] -> WT[E][C][R] ---------
__global__ __launch_bounds__(256) void k_transcvt(const float* __restrict__ W,
                                                  ushort* __restrict__ WT,
                                                  int R, int C) {
  __shared__ float t[64][65];
  int e = blockIdx.z;
  int c0 = blockIdx.x * 64, r0 = blockIdx.y * 64;
  const float* Wp = W + (size_t)e * R * C;
  ushort* Tp = WT + (size_t)e * R * C;
  int tx = threadIdx.x & 15, ty = threadIdx.x >> 4;
#pragma unroll
  for (int i = 0; i < 4; i++) {
    int lr = ty + i * 16;
    const float4 v = *(const float4*)&Wp[(size_t)(r0 + lr) * C + c0 + tx * 4];
    t[lr][tx * 4 + 0] = v.x; t[lr][tx * 4 + 1] = v.y;
    t[lr][tx * 4 + 2] = v.z; t[lr][tx * 4 + 3] = v.w;
  }
  __syncthreads();
#pragma unroll
  for (int i = 0; i < 4; i++) {
    int lc = ty + i * 16;
    ushort4 o;
    o.x = f2bf(t[tx * 4 + 0][lc]);
    o.y = f2bf(t[tx * 4 + 1][lc]);
    o.z = f2bf(t[tx * 4 + 2][lc]);
    o.w = f2bf(t[tx * 4 + 3][lc]);
    *(ushort4*)&Tp[(size_t)(c0 + lc) * R + r0 + tx * 4] = o;
  }
}

// ---------------- router ----------------------------------------------------
__global__ __launch_bounds__(256) void k_router(const float* __restrict__ x,
                                                const float* __restrict__ Wr,
                                                const float* __restrict__ br,
                                                const float* __restrict__ bbuf,
                                                int* cnt, int* te, float* tw) {
  int wid = threadIdx.x >> 6, lane = threadIdx.x & 63;
  int t = blockIdx.x * 4 + wid;
  const float* xp = x + (size_t)t * H_;
  double acc[E_];
#pragma unroll
  for (int e = 0; e < E_; e++) acc[e] = 0.0;
  for (int j = lane; j < H_; j += 64) {
    float xv = xp[j];
    const float4 w0 = *(const float4*)&Wr[j * 8];
    const float4 w1 = *(const float4*)&Wr[j * 8 + 4];
    acc[0] += (double)xv * (double)w0.x;
    acc[1] += (double)xv * (double)w0.y;
    acc[2] += (double)xv * (double)w0.z;
    acc[3] += (double)xv * (double)w0.w;
    acc[4] += (double)xv * (double)w1.x;
    acc[5] += (double)xv * (double)w1.y;
    acc[6] += (double)xv * (double)w1.z;
    acc[7] += (double)xv * (double)w1.w;
  }
#pragma unroll
  for (int e = 0; e < E_; e++)
    for (int s = 32; s > 0; s >>= 1) acc[e] += __shfl_xor(acc[e], s);
  if (lane == 0) {
    double s[E_], m = -1e300;
    for (int e = 0; e < E_; e++) { s[e] = acc[e] + (double)br[e]; if (s[e] > m) m = s[e]; }
    double pe[E_], sum = 0.0;
    for (int e = 0; e < E_; e++) { pe[e] = exp(s[e] - m); sum += pe[e]; }
    double pr[E_], bb[E_];
    for (int e = 0; e < E_; e++) { pr[e] = pe[e] / sum; bb[e] = pr[e] + (double)bbuf[e]; }
    int e0 = 0;
    for (int e = 1; e < E_; e++) if (bb[e] > bb[e0]) e0 = e;
    int e1 = (e0 == 0) ? 1 : 0;
    for (int e = 0; e < E_; e++) if (e != e0 && bb[e] > bb[e1]) e1 = e;
    int a0 = 0;
    for (int e = 1; e < E_; e++) if (pr[e] > pr[a0]) a0 = e;
    int a1 = (a0 == 0) ? 1 : 0;
    for (int e = 0; e < E_; e++) if (e != a0 && pr[e] > pr[a1]) a1 = e;
    double iv = 1.0 / (pr[a0] + pr[a1]);
    te[t * 2] = e0; te[t * 2 + 1] = e1;
    tw[t * 2] = (float)(pr[a0] * iv); tw[t * 2 + 1] = (float)(pr[a1] * iv);
    atomicAdd(&cnt[e0], 1); atomicAdd(&cnt[e1], 1);
  }
}

// ---------------- offsets: 256-padded virtual + compact prefix --------------
__global__ void k_offsets(const int* cnt, int* off, int* coff) {
  if (threadIdx.x == 0 && blockIdx.x == 0) {
    int o = 0, c = 0;
    for (int e = 0; e < E_; e++) {
      off[e] = o; coff[e] = c;
      o += ((cnt[e] + 255) >> 8) << 8;
      c += cnt[e];
    }
    off[E_] = o; coff[E_] = c;
  }
}

// ---------------- build token lists -----------------------------------------
__global__ void k_build(const int* __restrict__ te, const float* __restrict__ tw,
                        const int* __restrict__ off, const int* __restrict__ coff,
                        int* cur, int* tok, float* wl, int* v2c, int* ctok) {
  int t = blockIdx.x * 256 + threadIdx.x;
  if (t >= NTOK) return;
#pragma unroll
  for (int s = 0; s < 2; s++) {
    int e = te[t * 2 + s];
    int slot = atomicAdd(&cur[e], 1);
    int vp = off[e] + slot;
    int cp = coff[e] + slot;
    tok[vp] = t; wl[vp] = tw[t * 2 + s]; v2c[vp] = cp; ctok[cp] = t;
  }
}

// ---------------- gather x rows -> bf16 compact ------------------------------
__global__ __launch_bounds__(256) void k_gather(const float* __restrict__ x,
                                                const int* __restrict__ ctok,
                                                ushort* __restrict__ Xg) {
  int row = blockIdx.x;
  int t = ctok[row];
  const float4* src = (const float4*)(x + (size_t)t * H_);
  ushort4* dst = (ushort4*)(Xg + (size_t)row * H_);
  int i = threadIdx.x;
  float4 v = src[i];
  ushort4 o; o.x = f2bf(v.x); o.y = f2bf(v.y); o.z = f2bf(v.z); o.w = f2bf(v.w);
  dst[i] = o;
}

// ---------------- zero output ------------------------------------------------
__global__ void k_zero(float* out) {
  size_t i = (size_t)blockIdx.x * 256 + threadIdx.x;
  float4 z; z.x = 0.f; z.y = 0.f; z.z = 0.f; z.w = 0.f;
  ((float4*)out)[i] = z;
}

// ---------------- 256x128x64 MFMA GEMM, counted-vmcnt phased pipeline --------
// R4/R5 post-mortem: 512t block = 8 waves = 2 waves/SIMD -> 256 unified
// regs/wave cap. acc[8][4]=128 AGPR + >128 arch demand -> spill (1.7 GB
// scratch writeback). Fix: wave tile 64x64 -> acc[4][4] = 64 AGPR.
// Geometry: BM=256, BN=128, BK=64 (2 k-halves of 32). 8 waves = 4M x 2N.
// LDS/buffer: A[2 kss][256][32] 32KB + B[2][128][32] 16KB = 48KB; dbuf 96KB.
// Swizzle (both sides, rule #21): chunk' = chunk ^ sg(row), sg(r)=(r&3)^((r>>2)&3).
// Per half-phase/wave: 3 glds16 (issue next) -> 8 ds_read_b128 -> 16 MFMA ->
// vmcnt(3) + barrier. Always 3-6 loads in flight; never drains mid-loop.
// MODE 0: h1[v2c[row]] = gelu(A@B + b1[e]).  MODE 1: atomicAdd into Out.
template <int MODE>
__global__ __launch_bounds__(512) void k_gemm(const ushort* __restrict__ A,
                                              const ushort* __restrict__ BT,
                                              const float* __restrict__ bias,
                                              ushort* __restrict__ h1,
                                              float* __restrict__ Out,
                                              const int* __restrict__ off,
                                              const int* __restrict__ v2c,
                                              const int* __restrict__ tok,
                                              const float* __restrict__ wl,
                                              int K, int N, int NTe) {
  extern __shared__ char lds[];
  // ---- raster: XCD chunk, group-of-4 M, N (and split-K) fastest ----
  int nwg = gridDim.x;             // divisible by 8
  int cpx = nwg >> 3;
  int bid = blockIdx.x;
  int lid = (bid & 7) * cpx + (bid >> 3);
  int gsz = NTe << 2;
  int g = lid / gsz, r = lid % gsz;
  int ne = r >> 2, m = (g << 2) + (r & 3);
  int row0 = m << 8;
  if (row0 >= off[E_]) return;
  int e = 0;
  while (off[e + 1] <= row0) e++;
  int n0, k0, nk;
  if (MODE == 0) { n0 = ne << 7; k0 = 0; nk = K >> 6; }
  else           { n0 = (ne >> 1) << 7; k0 = (ne & 1) * (K >> 1); nk = K >> 7; }
  const ushort* Bp = BT + (size_t)e * (size_t)N * (size_t)K;

  int tid = threadIdx.x, lane = tid & 63, w = tid >> 6;
  int wr = w >> 1, wc = w & 1;      // 4 M-quadrants x 2 N-halves

  f32x4 acc[4][4];
#pragma unroll
  for (int mm = 0; mm < 4; mm++)
#pragma unroll
    for (int nn = 0; nn < 4; nn++) acc[mm][nn] = (f32x4){0.f, 0.f, 0.f, 0.f};

  // ---- staging addressing ----
  int ur = lane >> 2;                              // 0..15 row in 16-row unit
  int sgs = ((lane >> 2) & 3) ^ ((lane >> 4) & 3); // sg(ur)
  int sc = (lane & 3) ^ sgs;                       // pre-swizzled source chunk
  int vrA = row0 + (w << 5) + ur;                  // A rows: wave w owns 32
  int cr0 = v2c[vrA];      if (cr0 < 0) cr0 = 0;
  int cr1 = v2c[vrA + 16]; if (cr1 < 0) cr1 = 0;
  const char* aP0 = (const char*)(A + (size_t)cr0 * K) + k0 * 2 + sc * 16;
  const char* aP1 = (const char*)(A + (size_t)cr1 * K) + k0 * 2 + sc * 16;
  const char* bP0 = (const char*)(Bp + (size_t)(n0 + (w << 4) + ur) * K) + k0 * 2 + sc * 16;

  // ---- fragment read addressing (swizzled) ----
  int fr = lane & 15, fq = lane >> 4;
  int sgf = (fr & 3) ^ ((fr >> 2) & 3);
  int kchunk = (fq ^ sgf) << 3;                    // ushort offset within 32-row

#define STAGE(tt, kss, bb) do {                                        \
    size_t kb = (size_t)(tt) * 128 + (size_t)(kss) * 64;               \
    char* ab = lds + (bb) * 49152 + (kss) * 16384;                     \
    char* bbp = lds + (bb) * 49152 + 32768 + (kss) * 8192;             \
    glds16(aP0 + kb, ab + (w << 11));                                  \
    glds16(aP1 + kb, ab + (w << 11) + 1024);                           \
    glds16(bP0 + kb, bbp + (w << 10));                                 \
  } while (0)

#define COMPUTE(bb, kss) do {                                          \
    const ushort* LA = (const ushort*)(lds + (bb) * 49152 + (kss) * 16384); \
    const ushort* LB = (const ushort*)(lds + (bb) * 49152 + 32768 + (kss) * 8192); \
    short8 af[4], bfm[4];                                              \
    _Pragma("unroll")                                                  \
    for (int mm = 0; mm < 4; mm++)                                     \
      af[mm] = *(const short8*)&LA[((wr << 6) + mm * 16 + fr) * 32 + kchunk]; \
    _Pragma("unroll")                                                  \
    for (int nn = 0; nn < 4; nn++)                                     \
      bfm[nn] = *(const short8*)&LB[((wc << 6) + nn * 16 + fr) * 32 + kchunk]; \
    __builtin_amdgcn_s_setprio(1);                                     \
    _Pragma("unroll")                                                  \
    for (int mm = 0; mm < 4; mm++)                                     \
      _Pragma("unroll")                                                \
      for (int nn = 0; nn < 4; nn++)                                   \
        acc[mm][nn] = __builtin_amdgcn_mfma_f32_16x16x32_bf16(af[mm], bfm[nn], acc[mm][nn], 0, 0, 0); \
    __builtin_amdgcn_s_setprio(0);                                     \
  } while (0)

  // prologue: stage tile 0 (both K-halves) into buf 0
  STAGE(0, 0, 0);
  STAGE(0, 1, 0);
  asm volatile("s_waitcnt vmcnt(3)" ::: "memory");   // (0,ks0) landed
  __builtin_amdgcn_s_barrier();
  __builtin_amdgcn_sched_barrier(0);

  for (int t = 0; t < nk; t++) {
    int bb = t & 1;
    // ---- half-phase ks=0 ----
    if (t + 1 < nk) STAGE(t + 1, 0, bb ^ 1);
    COMPUTE(bb, 0);
    if (t + 1 < nk) asm volatile("s_waitcnt vmcnt(3)" ::: "memory");  // (t,ks1) landed
    else            asm volatile("s_waitcnt vmcnt(0)" ::: "memory");
    __builtin_amdgcn_s_barrier();
    __builtin_amdgcn_sched_barrier(0);
    // ---- half-phase ks=1 ----
    if (t + 1 < nk) {
      STAGE(t + 1, 1, bb ^ 1);
      COMPUTE(bb, 1);
      asm volatile("s_waitcnt vmcnt(3)" ::: "memory");                // (t+1,ks0) landed
      __builtin_amdgcn_s_barrier();
      __builtin_amdgcn_sched_barrier(0);
    } else {
      COMPUTE(bb, 1);
    }
  }
#undef STAGE
#undef COMPUTE

  // ---- epilogue ----
  const float* bp = bias + (size_t)e * N;
  int cbase = n0 + (wc << 6);
  if (MODE == 0) {
#pragma unroll
    for (int mm = 0; mm < 4; mm++) {
#pragma unroll
      for (int j = 0; j < 4; j++) {
        int vr = row0 + (wr << 6) + mm * 16 + (fq << 2) + j;
        int cr = v2c[vr];
        if (cr < 0) continue;
        ushort* hp = h1 + (size_t)cr * N + cbase;
#pragma unroll
        for (int nn = 0; nn < 4; nn++) {
          float v = acc[mm][nn][j] + bp[cbase + nn * 16 + fr];
          hp[nn * 16 + fr] = f2bf(gelu_t(v));
        }
      }
    }
  } else {
    bool addb = (k0 == 0);
#pragma unroll
    for (int mm = 0; mm < 4; mm++) {
#pragma unroll
      for (int j = 0; j < 4; j++) {
        int vr = row0 + (wr << 6) + mm * 16 + (fq << 2) + j;
        int t2 = tok[vr];
        if (t2 < 0) continue;
        float wgt = wl[vr];
#pragma unroll
        for (int nn = 0; nn < 4; nn++) {
          int c = cbase + nn * 16 + fr;
          float v = acc[mm][nn][j] + (addb ? bp[c] : 0.f);
          atomicAdd(&Out[(size_t)t2 * (size_t)N + c], wgt * v);
        }
      }
    }
  }
}

extern "C" void kernel_launch(void* const* d_in, const int* in_sizes, int n_in,
                              void* d_out, int out_size, void* d_ws, size_t ws_size,
                              hipStream_t stream) {
  (void)in_sizes; (void)n_in; (void)out_size; (void)ws_size;
  const float* x    = (const float*)d_in[0];
  const float* bbuf = (const float*)d_in[1];
  const float* Wr   = (const float*)d_in[2];
  const float* br   = (const float*)d_in[3];
  const float* W1   = (const float*)d_in[4];
  const float* b1   = (const float*)d_in[5];
  const float* W2   = (const float*)d_in[6];
  const float* b2   = (const float*)d_in[7];
  float* out = (float*)d_out;

  char* ws = (char*)d_ws;
  ushort* W1T = (ushort*)ws;                          // [E][F][H] bf16  64 MB
  ushort* W2T = (ushort*)(ws + 67108864);             // [E][H][F] bf16  64 MB
  ushort* Xg  = (ushort*)(ws + 134217728);            // [NCOMP][H] bf16 32 MB
  ushort* h1  = (ushort*)(ws + 167772160);            // [NCOMP][F] bf16 128 MB
  char* meta  = ws + 301989888;
  int*   cnt  = (int*)(meta);
  int*   off  = (int*)(meta + 64);
  int*   coff = (int*)(meta + 128);
  int*   cur  = (int*)(meta + 192);
  int*   te   = (int*)(meta + 256);                   // [NTOK*2]
  float* tw   = (float*)(meta + 65792);               // [NTOK*2]
  int*   tok  = (int*)(meta + 131328);                // [VCAP]
  float* wl   = (float*)(meta + 205056);              // [VCAP]
  int*   v2c  = (int*)(meta + 278784);                // [VCAP]
  int*   ctok = (int*)(meta + 352512);                // [NCOMP]

  hipFuncSetAttribute((const void*)&k_gemm<0>,
                      hipFuncAttributeMaxDynamicSharedMemorySize, 98304);
  hipFuncSetAttribute((const void*)&k_gemm<1>,
                      hipFuncAttributeMaxDynamicSharedMemorySize, 98304);

  k_init<<<VMBLK, 256, 0, stream>>>(cnt, cur, tok, wl, v2c);
  k_transcvt<<<dim3(F_ / 64, H_ / 64, E_), 256, 0, stream>>>(W1, W1T, H_, F_);
  k_transcvt<<<dim3(H_ / 64, F_ / 64, E_), 256, 0, stream>>>(W2, W2T, F_, H_);
  k_router<<<NTOK / 4, 256, 0, stream>>>(x, Wr, br, bbuf, cnt, te, tw);
  k_offsets<<<1, 64, 0, stream>>>(cnt, off, coff);
  k_build<<<NTOK / 256, 256, 0, stream>>>(te, tw, off, coff, cur, tok, wl, v2c, ctok);
  k_gather<<<NCOMP, 256, 0, stream>>>(x, ctok, Xg);
  k_zero<<<(NTOK * H_ / 4) / 256, 256, 0, stream>>>(out);
  // GEMM1: M=18432 virt, N=4096 (32 n-tiles of 128), K=1024. 32*72 = 2304 blocks
  k_gemm<0><<<32 * VMBLK, 512, 98304, stream>>>(Xg, W1T, b1, h1, nullptr,
                                                off, v2c, nullptr, nullptr,
                                                H_, F_, 32);
  // GEMM2: N=1024 (8 n-tiles), K=4096 split 2 -> NTe=16. 16*72 = 1152 blocks
  k_gemm<1><<<16 * VMBLK, 512, 98304, stream>>>(h1, W2T, b2, nullptr, out,
                                                off, v2c, tok, wl,
                                                F_, H_, 16);
}

// Round 7
// 1004.066 us; speedup vs baseline: 2.2657x; 1.0356x over previous
//
#include <hip/hip_runtime.h>
#include <stdint.h>

#define NTOK 8192
#define H_ 1024
#define F_ 4096
#define E_ 8
#define VCAP 18432      // 16384 slots + up to 8*256 padding (virtual rows)
#define VMBLK 72        // VCAP/256
#define NCOMP 16384     // compact rows (= NTOK * k exactly)

using f32x4  = __attribute__((ext_vector_type(4))) float;
using short8 = __attribute__((ext_vector_type(8))) short;

typedef __attribute__((address_space(1))) const uint32_t gu32;
typedef __attribute__((address_space(3))) uint32_t lu32;

__device__ __forceinline__ void glds16(const void* g, void* l) {
  __builtin_amdgcn_global_load_lds((gu32*)g, (lu32*)l, 16, 0, 0);
}

__device__ __forceinline__ ushort f2bf(float f) {
  union { float f; uint32_t u; } v; v.f = f;
  uint32_t r = (v.u + 0x7FFFu + ((v.u >> 16) & 1u)) >> 16;
  return (ushort)r;
}

__device__ __forceinline__ float gelu_t(float x) {
  float u = 0.7978845608028654f * (x + 0.044715f * x * x * x);
  float e = exp2f(u * 2.885390081777927f);      // exp(2u)
  float th = 1.0f - 2.0f / (1.0f + e);
  return 0.5f * x * (1.0f + th);
}

// ---------------- init ------------------------------------------------------
__global__ void k_init(int* cnt, int* cur, int* tok, float* wl, int* v2c) {
  int i = blockIdx.x * 256 + threadIdx.x;
  if (i < E_) { cnt[i] = 0; cur[i] = 0; }
  if (i < VCAP) { tok[i] = -1; wl[i] = 0.f; v2c[i] = -1; }
}

// ---------------- transpose + fp32->bf16: W[E][R][C] -> WT[E][C][R] ---------
__global__ __launch_bounds__(256) void k_transcvt(const float* __restrict__ W,
                                                  ushort* __restrict__ WT,
                                                  int R, int C) {
  __shared__ float t[64][65];
  int e = blockIdx.z;
  int c0 = blockIdx.x * 64, r0 = blockIdx.y * 64;
  const float* Wp = W + (size_t)e * R * C;
  ushort* Tp = WT + (size_t)e * R * C;
  int tx = threadIdx.x & 15, ty = threadIdx.x >> 4;
#pragma unroll
  for (int i = 0; i < 4; i++) {
    int lr = ty + i * 16;
    const float4 v = *(const float4*)&Wp[(size_t)(r0 + lr) * C + c0 + tx * 4];
    t[lr][tx * 4 + 0] = v.x; t[lr][tx * 4 + 1] = v.y;
    t[lr][tx * 4 + 2] = v.z; t[lr][tx * 4 + 3] = v.w;
  }
  __syncthreads();
#pragma unroll
  for (int i = 0; i < 4; i++) {
    int lc = ty + i * 16;
    ushort4 o;
    o.x = f2bf(t[tx * 4 + 0][lc]);
    o.y = f2bf(t[tx * 4 + 1][lc]);
    o.z = f2bf(t[tx * 4 + 2][lc]);
    o.w = f2bf(t[tx * 4 + 3][lc]);
    *(ushort4*)&Tp[(size_t)(c0 + lc) * R + r0 + tx * 4] = o;
  }
}

// ---------------- router ----------------------------------------------------
__global__ __launch_bounds__(256) void k_router(const float* __restrict__ x,
                                                const float* __restrict__ Wr,
                                                const float* __restrict__ br,
                                                const float* __restrict__ bbuf,
                                                int* cnt, int* te, float* tw) {
  int wid = threadIdx.x >> 6, lane = threadIdx.x & 63;
  int t = blockIdx.x * 4 + wid;
  const float* xp = x + (size_t)t * H_;
  double acc[E_];
#pragma unroll
  for (int e = 0; e < E_; e++) acc[e] = 0.0;
  for (int j = lane; j < H_; j += 64) {
    float xv = xp[j];
    const float4 w0 = *(const float4*)&Wr[j * 8];
    const float4 w1 = *(const float4*)&Wr[j * 8 + 4];
    acc[0] += (double)xv * (double)w0.x;
    acc[1] += (double)xv * (double)w0.y;
    acc[2] += (double)xv * (double)w0.z;
    acc[3] += (double)xv * (double)w0.w;
    acc[4] += (double)xv * (double)w1.x;
    acc[5] += (double)xv * (double)w1.y;
    acc[6] += (double)xv * (double)w1.z;
    acc[7] += (double)xv * (double)w1.w;
  }
#pragma unroll
  for (int e = 0; e < E_; e++)
    for (int s = 32; s > 0; s >>= 1) acc[e] += __shfl_xor(acc[e], s);
  if (lane == 0) {
    double s[E_], m = -1e300;
    for (int e = 0; e < E_; e++) { s[e] = acc[e] + (double)br[e]; if (s[e] > m) m = s[e]; }
    double pe[E_], sum = 0.0;
    for (int e = 0; e < E_; e++) { pe[e] = exp(s[e] - m); sum += pe[e]; }
    double pr[E_], bb[E_];
    for (int e = 0; e < E_; e++) { pr[e] = pe[e] / sum; bb[e] = pr[e] + (double)bbuf[e]; }
    int e0 = 0;
    for (int e = 1; e < E_; e++) if (bb[e] > bb[e0]) e0 = e;
    int e1 = (e0 == 0) ? 1 : 0;
    for (int e = 0; e < E_; e++) if (e != e0 && bb[e] > bb[e1]) e1 = e;
    int a0 = 0;
    for (int e = 1; e < E_; e++) if (pr[e] > pr[a0]) a0 = e;
    int a1 = (a0 == 0) ? 1 : 0;
    for (int e = 0; e < E_; e++) if (e != a0 && pr[e] > pr[a1]) a1 = e;
    double iv = 1.0 / (pr[a0] + pr[a1]);
    te[t * 2] = e0; te[t * 2 + 1] = e1;
    tw[t * 2] = (float)(pr[a0] * iv); tw[t * 2 + 1] = (float)(pr[a1] * iv);
    atomicAdd(&cnt[e0], 1); atomicAdd(&cnt[e1], 1);
  }
}

// ---------------- offsets: 256-padded virtual + compact prefix --------------
__global__ void k_offsets(const int* cnt, int* off, int* coff) {
  if (threadIdx.x == 0 && blockIdx.x == 0) {
    int o = 0, c = 0;
    for (int e = 0; e < E_; e++) {
      off[e] = o; coff[e] = c;
      o += ((cnt[e] + 255) >> 8) << 8;
      c += cnt[e];
    }
    off[E_] = o; coff[E_] = c;
  }
}

// ---------------- build token lists -----------------------------------------
__global__ void k_build(const int* __restrict__ te, const float* __restrict__ tw,
                        const int* __restrict__ off, const int* __restrict__ coff,
                        int* cur, int* tok, float* wl, int* v2c, int* ctok) {
  int t = blockIdx.x * 256 + threadIdx.x;
  if (t >= NTOK) return;
#pragma unroll
  for (int s = 0; s < 2; s++) {
    int e = te[t * 2 + s];
    int slot = atomicAdd(&cur[e], 1);
    int vp = off[e] + slot;
    int cp = coff[e] + slot;
    tok[vp] = t; wl[vp] = tw[t * 2 + s]; v2c[vp] = cp; ctok[cp] = t;
  }
}

// ---------------- gather x rows -> bf16 compact ------------------------------
__global__ __launch_bounds__(256) void k_gather(const float* __restrict__ x,
                                                const int* __restrict__ ctok,
                                                ushort* __restrict__ Xg) {
  int row = blockIdx.x;
  int t = ctok[row];
  const float4* src = (const float4*)(x + (size_t)t * H_);
  ushort4* dst = (ushort4*)(Xg + (size_t)row * H_);
  int i = threadIdx.x;
  float4 v = src[i];
  ushort4 o; o.x = f2bf(v.x); o.y = f2bf(v.y); o.z = f2bf(v.z); o.w = f2bf(v.w);
  dst[i] = o;
}

// ---------------- zero output ------------------------------------------------
__global__ void k_zero(float* out) {
  size_t i = (size_t)blockIdx.x * 256 + threadIdx.x;
  float4 z; z.x = 0.f; z.y = 0.f; z.z = 0.f; z.w = 0.f;
  ((float4*)out)[i] = z;
}

// ---------------- 256x256x64 MFMA GEMM, 4-phase counted-vmcnt pipeline -------
// m201-class geometry: 8 waves (2M x 4N), per-wave 128x64, acc[8][4] (128 AGPR).
// LDS: 2 dbuf x (A 256x64 + B 256x64) bf16 = 128 KB. Rows are 128 B (8 chunks
// of 16 B); swizzle chunk ^= row&7 (R3-verified: 0 bank conflicts), glds dest
// linear + pre-swizzled global source (rule #21).
// Per K-tile, 4 phases (quadrants): p0 A0-3xB01, p1 A4-7xB01, p2 A4-7xB23,
// p3 A0-3xB23. Staging next tile 2 units/phase in order B0B1,B2B3,A0A2,A1A3
// (unit = 64 rows = 8 KB). Counted waits: vmcnt(2) at p0 (covers A1,A3 of
// current tile) and p3 (covers B0-3,A0,A2 of next tile). Never drains mid-loop.
// MODE 0: h1[v2c[row]] = gelu(A@B + b1[e]).  MODE 1: atomicAdd into Out.
template <int MODE>
__global__ __launch_bounds__(512) void k_gemm(const ushort* __restrict__ A,
                                              const ushort* __restrict__ BT,
                                              const float* __restrict__ bias,
                                              ushort* __restrict__ h1,
                                              float* __restrict__ Out,
                                              const int* __restrict__ off,
                                              const int* __restrict__ v2c,
                                              const int* __restrict__ tok,
                                              const float* __restrict__ wl,
                                              int K, int N, int NTe) {
  extern __shared__ char lds[];
  // ---- raster: XCD chunk, group-of-4 M, n-id fastest ----
  int nwg = gridDim.x;             // divisible by 8
  int cpx = nwg >> 3;
  int bid = blockIdx.x;
  int lid = (bid & 7) * cpx + (bid >> 3);
  int gsz = NTe << 2;
  int g = lid / gsz, rm = lid % gsz;
  int ne = rm >> 2, m = (g << 2) + (rm & 3);
  int row0 = m << 8;
  if (row0 >= off[E_]) return;
  int e = 0;
  while (off[e + 1] <= row0) e++;
  int n0, k0, nk;
  if (MODE == 0) { n0 = ne << 8; k0 = 0; nk = K >> 6; }
  else           { n0 = (ne >> 1) << 8; k0 = (ne & 1) * (K >> 1); nk = K >> 7; }
  const ushort* Bp = BT + (size_t)e * (size_t)N * (size_t)K;

  int tid = threadIdx.x, lane = tid & 63, w = tid >> 6;
  int wr = w >> 2, wc = w & 3;     // 2 M-halves x 4 N-quarters

  f32x4 acc[8][4];
#pragma unroll
  for (int mm = 0; mm < 8; mm++)
#pragma unroll
    for (int nn = 0; nn < 4; nn++) acc[mm][nn] = (f32x4){0.f, 0.f, 0.f, 0.f};

  // ---- staging addressing: unit = 64 rows x 128 B = 8 KB; thread covers 16 B
  int urow = (w << 3) + (lane >> 3);        // 0..63 row within unit
  int schunk = (lane & 7) ^ (lane >> 3);    // pre-swizzled source chunk
  const char *aS0, *aS1, *aS2, *aS3, *bS0, *bS1, *bS2, *bS3;
  {
    int v0 = v2c[row0 + 0 * 64 + urow];   if (v0 < 0) v0 = 0;
    int v1 = v2c[row0 + 1 * 64 + urow];   if (v1 < 0) v1 = 0;
    int v2 = v2c[row0 + 2 * 64 + urow];   if (v2 < 0) v2 = 0;
    int v3 = v2c[row0 + 3 * 64 + urow];   if (v3 < 0) v3 = 0;
    size_t kb = (size_t)k0 * 2 + (size_t)schunk * 16;
    aS0 = (const char*)(A + (size_t)v0 * K) + kb;
    aS1 = (const char*)(A + (size_t)v1 * K) + kb;
    aS2 = (const char*)(A + (size_t)v2 * K) + kb;
    aS3 = (const char*)(A + (size_t)v3 * K) + kb;
    bS0 = (const char*)(Bp + (size_t)(n0 + 0 * 64 + urow) * K) + kb;
    bS1 = (const char*)(Bp + (size_t)(n0 + 1 * 64 + urow) * K) + kb;
    bS2 = (const char*)(Bp + (size_t)(n0 + 2 * 64 + urow) * K) + kb;
    bS3 = (const char*)(Bp + (size_t)(n0 + 3 * 64 + urow) * K) + kb;
  }

  // ---- fragment read addressing ----
  int fr = lane & 15, fq = lane >> 4;
  int frs = fr & 7;

  short8 af_[4][2], bf_[2][2];

#define STG_A(u, tt, bbuf) glds16(aS##u + (size_t)(tt) * 128, lds + (bbuf) * 65536 + (u) * 8192 + (w << 10))
#define STG_B(u, tt, bbuf) glds16(bS##u + (size_t)(tt) * 128, lds + (bbuf) * 65536 + 32768 + (u) * 8192 + (w << 10))

#define RDA(mmq, bbuf) do {                                                  \
    const ushort* LA_ = (const ushort*)(lds + (bbuf) * 65536);               \
    _Pragma("unroll")                                                        \
    for (int i = 0; i < 4; ++i)                                              \
      _Pragma("unroll")                                                      \
      for (int ks = 0; ks < 2; ++ks)                                         \
        af_[i][ks] = *(const short8*)&LA_[((wr << 7) + ((mmq) + i) * 16 + fr) * 64 + (((ks << 2) + fq) ^ frs) * 8]; \
  } while (0)

#define RDB(nnq, bbuf) do {                                                  \
    const ushort* LB_ = (const ushort*)(lds + (bbuf) * 65536 + 32768);       \
    _Pragma("unroll")                                                        \
    for (int i = 0; i < 2; ++i)                                              \
      _Pragma("unroll")                                                      \
      for (int ks = 0; ks < 2; ++ks)                                         \
        bf_[i][ks] = *(const short8*)&LB_[((wc << 6) + ((nnq) + i) * 16 + fr) * 64 + (((ks << 2) + fq) ^ frs) * 8]; \
  } while (0)

#define MMQ(mmq, nnq) do {                                                   \
    __builtin_amdgcn_s_setprio(1);                                           \
    _Pragma("unroll")                                                        \
    for (int i = 0; i < 4; ++i)                                              \
      _Pragma("unroll")                                                      \
      for (int jn = 0; jn < 2; ++jn)                                         \
        _Pragma("unroll")                                                    \
        for (int ks = 0; ks < 2; ++ks)                                       \
          acc[(mmq) + i][(nnq) + jn] = __builtin_amdgcn_mfma_f32_16x16x32_bf16(af_[i][ks], bf_[jn][ks], acc[(mmq) + i][(nnq) + jn], 0, 0, 0); \
    __builtin_amdgcn_s_setprio(0);                                           \
  } while (0)

#define FENCE() __builtin_amdgcn_sched_barrier(0)
#define BAR()   __builtin_amdgcn_s_barrier()

  // ---- prologue: stage tile 0 into buf 0; wait all but A1,A3 ----
  STG_B(0, 0, 0); STG_B(1, 0, 0); STG_B(2, 0, 0); STG_B(3, 0, 0);
  STG_A(0, 0, 0); STG_A(2, 0, 0); STG_A(1, 0, 0); STG_A(3, 0, 0);
  asm volatile("s_waitcnt vmcnt(2)" ::: "memory");
  BAR(); FENCE();

  for (int t = 0; t < nk; ++t) {
    int bb = t & 1, nb = bb ^ 1;
    bool pre = (t + 1 < nk);
    // ---- p0: A0-3 x B01 ----
    if (pre) { STG_B(0, t + 1, nb); STG_B(1, t + 1, nb); }
    RDB(0, bb); RDA(0, bb);
    MMQ(0, 0);
    FENCE();
    if (pre) asm volatile("s_waitcnt vmcnt(2)" ::: "memory");  // A1,A3 of tile t
    else     asm volatile("s_waitcnt vmcnt(0)" ::: "memory");
    BAR(); FENCE();
    // ---- p1: A4-7 x B01 ----
    if (pre) { STG_B(2, t + 1, nb); STG_B(3, t + 1, nb); }
    RDA(4, bb);
    MMQ(4, 0);
    FENCE(); BAR(); FENCE();
    // ---- p2: A4-7 x B23 ----
    if (pre) { STG_A(0, t + 1, nb); STG_A(2, t + 1, nb); }
    RDB(2, bb);
    MMQ(4, 2);
    FENCE(); BAR(); FENCE();
    // ---- p3: A0-3 x B23 ----
    if (pre) { STG_A(1, t + 1, nb); STG_A(3, t + 1, nb); }
    RDA(0, bb);
    MMQ(0, 2);
    FENCE();
    if (pre) asm volatile("s_waitcnt vmcnt(2)" ::: "memory");  // B0-3,A0,A2 of t+1
    BAR(); FENCE();
  }
#undef STG_A
#undef STG_B
#undef RDA
#undef RDB
#undef MMQ
#undef FENCE
#undef BAR

  // ---- epilogue ----
  const float* bp = bias + (size_t)e * N;
  int cb = n0 + (wc << 6);
  if (MODE == 0) {
#pragma unroll
    for (int mm = 0; mm < 8; mm++) {
#pragma unroll
      for (int j = 0; j < 4; j++) {
        int vr = row0 + (wr << 7) + mm * 16 + (fq << 2) + j;
        int cr = v2c[vr];
        if (cr < 0) continue;
        ushort* hp = h1 + (size_t)cr * N + cb;
#pragma unroll
        for (int nn = 0; nn < 4; nn++) {
          float v = acc[mm][nn][j] + bp[cb + nn * 16 + fr];
          hp[nn * 16 + fr] = f2bf(gelu_t(v));
        }
      }
    }
  } else {
    bool addb = (k0 == 0);
#pragma unroll
    for (int mm = 0; mm < 8; mm++) {
#pragma unroll
      for (int j = 0; j < 4; j++) {
        int vr = row0 + (wr << 7) + mm * 16 + (fq << 2) + j;
        int t2 = tok[vr];
        if (t2 < 0) continue;
        float wgt = wl[vr];
#pragma unroll
        for (int nn = 0; nn < 4; nn++) {
          int c = cb + nn * 16 + fr;
          float v = acc[mm][nn][j] + (addb ? bp[c] : 0.f);
          atomicAdd(&Out[(size_t)t2 * (size_t)N + c], wgt * v);
        }
      }
    }
  }
}

extern "C" void kernel_launch(void* const* d_in, const int* in_sizes, int n_in,
                              void* d_out, int out_size, void* d_ws, size_t ws_size,
                              hipStream_t stream) {
  (void)in_sizes; (void)n_in; (void)out_size; (void)ws_size;
  const float* x    = (const float*)d_in[0];
  const float* bbuf = (const float*)d_in[1];
  const float* Wr   = (const float*)d_in[2];
  const float* br   = (const float*)d_in[3];
  const float* W1   = (const float*)d_in[4];
  const float* b1   = (const float*)d_in[5];
  const float* W2   = (const float*)d_in[6];
  const float* b2   = (const float*)d_in[7];
  float* out = (float*)d_out;

  char* ws = (char*)d_ws;
  ushort* W1T = (ushort*)ws;                          // [E][F][H] bf16  64 MB
  ushort* W2T = (ushort*)(ws + 67108864);             // [E][H][F] bf16  64 MB
  ushort* Xg  = (ushort*)(ws + 134217728);            // [NCOMP][H] bf16 32 MB
  ushort* h1  = (ushort*)(ws + 167772160);            // [NCOMP][F] bf16 128 MB
  char* meta  = ws + 301989888;
  int*   cnt  = (int*)(meta);
  int*   off  = (int*)(meta + 64);
  int*   coff = (int*)(meta + 128);
  int*   cur  = (int*)(meta + 192);
  int*   te   = (int*)(meta + 256);                   // [NTOK*2]
  float* tw   = (float*)(meta + 65792);               // [NTOK*2]
  int*   tok  = (int*)(meta + 131328);                // [VCAP]
  float* wl   = (float*)(meta + 205056);              // [VCAP]
  int*   v2c  = (int*)(meta + 278784);                // [VCAP]
  int*   ctok = (int*)(meta + 352512);                // [NCOMP]

  hipFuncSetAttribute((const void*)&k_gemm<0>,
                      hipFuncAttributeMaxDynamicSharedMemorySize, 131072);
  hipFuncSetAttribute((const void*)&k_gemm<1>,
                      hipFuncAttributeMaxDynamicSharedMemorySize, 131072);

  k_init<<<VMBLK, 256, 0, stream>>>(cnt, cur, tok, wl, v2c);
  k_transcvt<<<dim3(F_ / 64, H_ / 64, E_), 256, 0, stream>>>(W1, W1T, H_, F_);
  k_transcvt<<<dim3(H_ / 64, F_ / 64, E_), 256, 0, stream>>>(W2, W2T, F_, H_);
  k_router<<<NTOK / 4, 256, 0, stream>>>(x, Wr, br, bbuf, cnt, te, tw);
  k_offsets<<<1, 64, 0, stream>>>(cnt, off, coff);
  k_build<<<NTOK / 256, 256, 0, stream>>>(te, tw, off, coff, cur, tok, wl, v2c, ctok);
  k_gather<<<NCOMP, 256, 0, stream>>>(x, ctok, Xg);
  k_zero<<<(NTOK * H_ / 4) / 256, 256, 0, stream>>>(out);
  // GEMM1: M=18432 virt, N=4096 (16 n-tiles of 256), K=1024 (16 K-tiles).
  k_gemm<0><<<16 * VMBLK, 512, 131072, stream>>>(Xg, W1T, b1, h1, nullptr,
                                                 off, v2c, nullptr, nullptr,
                                                 H_, F_, 16);
  // GEMM2: N=1024 (4 n-tiles of 256) x split-K 2, K=4096 (32 K-tiles/split).
  k_gemm<1><<<8 * VMBLK, 512, 131072, stream>>>(h1, W2T, b2, nullptr, out,
                                                off, v2c, tok, wl,
                                                F_, H_, 8);
}

// Round 8
// 998.487 us; speedup vs baseline: 2.2784x; 1.0056x over previous
//
#include <hip/hip_runtime.h>
#include <stdint.h>

#define NTOK 8192
#define H_ 1024
#define F_ 4096
#define E_ 8
#define VCAP 18432      // 16384 slots + up to 8*256 padding (virtual rows)
#define VMBLK 72        // VCAP/256
#define NCOMP 16384     // compact rows (= NTOK * k exactly)

using f32x4  = __attribute__((ext_vector_type(4))) float;
using short8 = __attribute__((ext_vector_type(8))) short;

typedef __attribute__((address_space(1))) const uint32_t gu32;
typedef __attribute__((address_space(3))) uint32_t lu32;

__device__ __forceinline__ void glds16(const void* g, void* l) {
  __builtin_amdgcn_global_load_lds((gu32*)g, (lu32*)l, 16, 0, 0);
}

__device__ __forceinline__ ushort f2bf(float f) {
  union { float f; uint32_t u; } v; v.f = f;
  uint32_t r = (v.u + 0x7FFFu + ((v.u >> 16) & 1u)) >> 16;
  return (ushort)r;
}

__device__ __forceinline__ float gelu_t(float x) {
  float u = 0.7978845608028654f * (x + 0.044715f * x * x * x);
  float e = exp2f(u * 2.885390081777927f);      // exp(2u)
  float th = 1.0f - 2.0f / (1.0f + e);
  return 0.5f * x * (1.0f + th);
}

// ---------------- init ------------------------------------------------------
__global__ void k_init(int* cnt, int* cur, int* tok, float* wl, int* v2c) {
  int i = blockIdx.x * 256 + threadIdx.x;
  if (i < E_) { cnt[i] = 0; cur[i] = 0; }
  if (i < VCAP) { tok[i] = -1; wl[i] = 0.f; v2c[i] = -1; }
}

// ---------------- transpose + fp32->bf16: W[E][R][C] -> WT[E][C][R] ---------
__global__ __launch_bounds__(256) void k_transcvt(const float* __restrict__ W,
                                                  ushort* __restrict__ WT,
                                                  int R, int C) {
  __shared__ float t[64][65];
  int e = blockIdx.z;
  int c0 = blockIdx.x * 64, r0 = blockIdx.y * 64;
  const float* Wp = W + (size_t)e * R * C;
  ushort* Tp = WT + (size_t)e * R * C;
  int tx = threadIdx.x & 15, ty = threadIdx.x >> 4;
#pragma unroll
  for (int i = 0; i < 4; i++) {
    int lr = ty + i * 16;
    const float4 v = *(const float4*)&Wp[(size_t)(r0 + lr) * C + c0 + tx * 4];
    t[lr][tx * 4 + 0] = v.x; t[lr][tx * 4 + 1] = v.y;
    t[lr][tx * 4 + 2] = v.z; t[lr][tx * 4 + 3] = v.w;
  }
  __syncthreads();
#pragma unroll
  for (int i = 0; i < 4; i++) {
    int lc = ty + i * 16;
    ushort4 o;
    o.x = f2bf(t[tx * 4 + 0][lc]);
    o.y = f2bf(t[tx * 4 + 1][lc]);
    o.z = f2bf(t[tx * 4 + 2][lc]);
    o.w = f2bf(t[tx * 4 + 3][lc]);
    *(ushort4*)&Tp[(size_t)(c0 + lc) * R + r0 + tx * 4] = o;
  }
}

// ---------------- router ----------------------------------------------------
__global__ __launch_bounds__(256) void k_router(const float* __restrict__ x,
                                                const float* __restrict__ Wr,
                                                const float* __restrict__ br,
                                                const float* __restrict__ bbuf,
                                                int* cnt, int* te, float* tw) {
  int wid = threadIdx.x >> 6, lane = threadIdx.x & 63;
  int t = blockIdx.x * 4 + wid;
  const float* xp = x + (size_t)t * H_;
  double acc[E_];
#pragma unroll
  for (int e = 0; e < E_; e++) acc[e] = 0.0;
  for (int j = lane; j < H_; j += 64) {
    float xv = xp[j];
    const float4 w0 = *(const float4*)&Wr[j * 8];
    const float4 w1 = *(const float4*)&Wr[j * 8 + 4];
    acc[0] += (double)xv * (double)w0.x;
    acc[1] += (double)xv * (double)w0.y;
    acc[2] += (double)xv * (double)w0.z;
    acc[3] += (double)xv * (double)w0.w;
    acc[4] += (double)xv * (double)w1.x;
    acc[5] += (double)xv * (double)w1.y;
    acc[6] += (double)xv * (double)w1.z;
    acc[7] += (double)xv * (double)w1.w;
  }
#pragma unroll
  for (int e = 0; e < E_; e++)
    for (int s = 32; s > 0; s >>= 1) acc[e] += __shfl_xor(acc[e], s);
  if (lane == 0) {
    double s[E_], m = -1e300;
    for (int e = 0; e < E_; e++) { s[e] = acc[e] + (double)br[e]; if (s[e] > m) m = s[e]; }
    double pe[E_], sum = 0.0;
    for (int e = 0; e < E_; e++) { pe[e] = exp(s[e] - m); sum += pe[e]; }
    double pr[E_], bb[E_];
    for (int e = 0; e < E_; e++) { pr[e] = pe[e] / sum; bb[e] = pr[e] + (double)bbuf[e]; }
    int e0 = 0;
    for (int e = 1; e < E_; e++) if (bb[e] > bb[e0]) e0 = e;
    int e1 = (e0 == 0) ? 1 : 0;
    for (int e = 0; e < E_; e++) if (e != e0 && bb[e] > bb[e1]) e1 = e;
    int a0 = 0;
    for (int e = 1; e < E_; e++) if (pr[e] > pr[a0]) a0 = e;
    int a1 = (a0 == 0) ? 1 : 0;
    for (int e = 0; e < E_; e++) if (e != a0 && pr[e] > pr[a1]) a1 = e;
    double iv = 1.0 / (pr[a0] + pr[a1]);
    te[t * 2] = e0; te[t * 2 + 1] = e1;
    tw[t * 2] = (float)(pr[a0] * iv); tw[t * 2 + 1] = (float)(pr[a1] * iv);
    atomicAdd(&cnt[e0], 1); atomicAdd(&cnt[e1], 1);
  }
}

// ---------------- offsets: 256-padded virtual + compact prefix --------------
__global__ void k_offsets(const int* cnt, int* off, int* coff) {
  if (threadIdx.x == 0 && blockIdx.x == 0) {
    int o = 0, c = 0;
    for (int e = 0; e < E_; e++) {
      off[e] = o; coff[e] = c;
      o += ((cnt[e] + 255) >> 8) << 8;
      c += cnt[e];
    }
    off[E_] = o; coff[E_] = c;
  }
}

// ---------------- build token lists -----------------------------------------
__global__ void k_build(const int* __restrict__ te, const float* __restrict__ tw,
                        const int* __restrict__ off, const int* __restrict__ coff,
                        int* cur, int* tok, float* wl, int* v2c, int* ctok) {
  int t = blockIdx.x * 256 + threadIdx.x;
  if (t >= NTOK) return;
#pragma unroll
  for (int s = 0; s < 2; s++) {
    int e = te[t * 2 + s];
    int slot = atomicAdd(&cur[e], 1);
    int vp = off[e] + slot;
    int cp = coff[e] + slot;
    tok[vp] = t; wl[vp] = tw[t * 2 + s]; v2c[vp] = cp; ctok[cp] = t;
  }
}

// ---------------- gather x rows -> bf16 compact ------------------------------
__global__ __launch_bounds__(256) void k_gather(const float* __restrict__ x,
                                                const int* __restrict__ ctok,
                                                ushort* __restrict__ Xg) {
  int row = blockIdx.x;
  int t = ctok[row];
  const float4* src = (const float4*)(x + (size_t)t * H_);
  ushort4* dst = (ushort4*)(Xg + (size_t)row * H_);
  int i = threadIdx.x;
  float4 v = src[i];
  ushort4 o; o.x = f2bf(v.x); o.y = f2bf(v.y); o.z = f2bf(v.z); o.w = f2bf(v.w);
  dst[i] = o;
}

// ---------------- zero output ------------------------------------------------
__global__ void k_zero(float* out) {
  size_t i = (size_t)blockIdx.x * 256 + threadIdx.x;
  float4 z; z.x = 0.f; z.y = 0.f; z.z = 0.f; z.w = 0.f;
  ((float4*)out)[i] = z;
}

// ---------------- 256x256x64 MFMA GEMM, m201-style reads->BAR->MFMA ----------
// R7 post-mortem: BAR->ds_read->MFMA->BAR serialized LDS and MFMA per phase
// (MfmaUtil 15%). This round: per tile T:
//   stage A-odd(T+1); vmcnt(8); BAR          (all 8 waves' tile-T glds landed)
//   16 ds_read (A m0-3 + B all); lgkm(0); BAR (reads done -> stages can write)
//   16 MFMA; stage B01(T+2); 16 MFMA; stage B23(T+2)
//   8 ds_read (A m4-7); lgkm(0); BAR
//   16 MFMA; stage A-even(T+2); 16 MFMA
// MFMA clusters drain while the next read/stage burst issues (pipes overlap).
// vmcnt(8): exactly the 8 newer unit-loads (B01,B23,Aeven of T+1 + Aodd of
// T+1) remain; ~2-tile prefetch slack. All stages write regions whose readers
// passed a lgkm(0)+BAR. Swizzle/addressing/epilogue identical to R7 (0 conf).
template <int MODE>
__global__ __launch_bounds__(512) void k_gemm(const ushort* __restrict__ A,
                                              const ushort* __restrict__ BT,
                                              const float* __restrict__ bias,
                                              ushort* __restrict__ h1,
                                              float* __restrict__ Out,
                                              const int* __restrict__ off,
                                              const int* __restrict__ v2c,
                                              const int* __restrict__ tok,
                                              const float* __restrict__ wl,
                                              int K, int N, int NTe) {
  extern __shared__ char lds[];
  // ---- raster: XCD chunk, group-of-4 M, n-id fastest ----
  int nwg = gridDim.x;             // divisible by 8
  int cpx = nwg >> 3;
  int bid = blockIdx.x;
  int lid = (bid & 7) * cpx + (bid >> 3);
  int gsz = NTe << 2;
  int g = lid / gsz, rm = lid % gsz;
  int ne = rm >> 2, m = (g << 2) + (rm & 3);
  int row0 = m << 8;
  if (row0 >= off[E_]) return;
  int e = 0;
  while (off[e + 1] <= row0) e++;
  int n0, k0, nk;
  if (MODE == 0) { n0 = ne << 8; k0 = 0; nk = K >> 6; }
  else           { n0 = (ne >> 1) << 8; k0 = (ne & 1) * (K >> 1); nk = K >> 7; }
  const ushort* Bp = BT + (size_t)e * (size_t)N * (size_t)K;

  int tid = threadIdx.x, lane = tid & 63, w = tid >> 6;
  int wr = w >> 2, wc = w & 3;     // 2 M-halves x 4 N-quarters

  f32x4 acc[8][4];
#pragma unroll
  for (int mm = 0; mm < 8; mm++)
#pragma unroll
    for (int nn = 0; nn < 4; nn++) acc[mm][nn] = (f32x4){0.f, 0.f, 0.f, 0.f};

  // ---- staging addressing: unit = 64 rows x 128 B = 8 KB; thread covers 16 B
  int urow = (w << 3) + (lane >> 3);        // 0..63 row within unit
  int schunk = (lane & 7) ^ (lane >> 3);    // pre-swizzled source chunk
  const char *aS0, *aS1, *aS2, *aS3, *bS0, *bS1, *bS2, *bS3;
  {
    int v0 = v2c[row0 + 0 * 64 + urow];   if (v0 < 0) v0 = 0;
    int v1 = v2c[row0 + 1 * 64 + urow];   if (v1 < 0) v1 = 0;
    int v2 = v2c[row0 + 2 * 64 + urow];   if (v2 < 0) v2 = 0;
    int v3 = v2c[row0 + 3 * 64 + urow];   if (v3 < 0) v3 = 0;
    size_t kb = (size_t)k0 * 2 + (size_t)schunk * 16;
    aS0 = (const char*)(A + (size_t)v0 * K) + kb;
    aS1 = (const char*)(A + (size_t)v1 * K) + kb;
    aS2 = (const char*)(A + (size_t)v2 * K) + kb;
    aS3 = (const char*)(A + (size_t)v3 * K) + kb;
    bS0 = (const char*)(Bp + (size_t)(n0 + 0 * 64 + urow) * K) + kb;
    bS1 = (const char*)(Bp + (size_t)(n0 + 1 * 64 + urow) * K) + kb;
    bS2 = (const char*)(Bp + (size_t)(n0 + 2 * 64 + urow) * K) + kb;
    bS3 = (const char*)(Bp + (size_t)(n0 + 3 * 64 + urow) * K) + kb;
  }

  // ---- fragment read addressing ----
  int fr = lane & 15, fq = lane >> 4;
  int frs = fr & 7;

  short8 af_[4][2], bf_[4][2];

#define STG_A(u, tt, bbuf) glds16(aS##u + (size_t)(tt) * 128, lds + (bbuf) * 65536 + (u) * 8192 + (w << 10))
#define STG_B(u, tt, bbuf) glds16(bS##u + (size_t)(tt) * 128, lds + (bbuf) * 65536 + 32768 + (u) * 8192 + (w << 10))

#define RDA(mmq, bbuf) do {                                                  \
    const ushort* LA_ = (const ushort*)(lds + (bbuf) * 65536);               \
    _Pragma("unroll")                                                        \
    for (int i = 0; i < 4; ++i)                                              \
      _Pragma("unroll")                                                      \
      for (int ks = 0; ks < 2; ++ks)                                         \
        af_[i][ks] = *(const short8*)&LA_[((wr << 7) + ((mmq) + i) * 16 + fr) * 64 + (((ks << 2) + fq) ^ frs) * 8]; \
  } while (0)

#define RDB(bbuf) do {                                                       \
    const ushort* LB_ = (const ushort*)(lds + (bbuf) * 65536 + 32768);       \
    _Pragma("unroll")                                                        \
    for (int i = 0; i < 4; ++i)                                              \
      _Pragma("unroll")                                                      \
      for (int ks = 0; ks < 2; ++ks)                                         \
        bf_[i][ks] = *(const short8*)&LB_[((wc << 6) + i * 16 + fr) * 64 + (((ks << 2) + fq) ^ frs) * 8]; \
  } while (0)

#define MMQ(mmq, nnq) do {                                                   \
    __builtin_amdgcn_s_setprio(1);                                           \
    _Pragma("unroll")                                                        \
    for (int i = 0; i < 4; ++i)                                              \
      _Pragma("unroll")                                                      \
      for (int jn = 0; jn < 2; ++jn)                                         \
        _Pragma("unroll")                                                    \
        for (int ks = 0; ks < 2; ++ks)                                       \
          acc[(mmq) + i][(nnq) + jn] = __builtin_amdgcn_mfma_f32_16x16x32_bf16(af_[i][ks], bf_[(nnq) + jn][ks], acc[(mmq) + i][(nnq) + jn], 0, 0, 0); \
    __builtin_amdgcn_s_setprio(0);                                           \
  } while (0)

#define FENCE() __builtin_amdgcn_sched_barrier(0)
#define BAR()   __builtin_amdgcn_s_barrier()
#define WAIT_LGKM() asm volatile("s_waitcnt lgkmcnt(0)" ::: "memory")

  // ---- prologue: T0 all 8 units -> buf0; T1 B0-3,A0,A2 -> buf1 ----
  STG_B(0, 0, 0); STG_B(1, 0, 0); STG_B(2, 0, 0); STG_B(3, 0, 0);
  STG_A(0, 0, 0); STG_A(1, 0, 0); STG_A(2, 0, 0); STG_A(3, 0, 0);
  if (nk > 1) {
    STG_B(0, 1, 1); STG_B(1, 1, 1); STG_B(2, 1, 1); STG_B(3, 1, 1);
    STG_A(0, 1, 1); STG_A(2, 1, 1);
  }

  for (int T = 0; T < nk; ++T) {
    int bb = T & 1, nb = bb ^ 1;
    bool s1 = (T + 1 < nk), s2 = (T + 2 < nk);
    // ---- top: complete T+1 (A-odd), wait tile T, publish ----
    if (s1) { STG_A(1, T + 1, nb); STG_A(3, T + 1, nb); }
    if (s1) asm volatile("s_waitcnt vmcnt(8)" ::: "memory");
    else    asm volatile("s_waitcnt vmcnt(0)" ::: "memory");
    BAR(); FENCE();
    // ---- read block 1: A m0-3 + all B (16 b128) ----
    RDA(0, bb); RDB(bb);
    WAIT_LGKM(); FENCE();
    BAR(); FENCE();
    // ---- compute half 1, stage B of T+2 ----
    MMQ(0, 0);
    if (s2) { STG_B(0, T + 2, bb); STG_B(1, T + 2, bb); }
    MMQ(0, 2);
    if (s2) { STG_B(2, T + 2, bb); STG_B(3, T + 2, bb); }
    // ---- read block 2: A m4-7 (8 b128) ----
    RDA(4, bb);
    WAIT_LGKM(); FENCE();
    BAR(); FENCE();
    // ---- compute half 2, stage A-even of T+2 ----
    MMQ(4, 0);
    if (s2) { STG_A(0, T + 2, bb); STG_A(2, T + 2, bb); }
    MMQ(4, 2);
  }
#undef STG_A
#undef STG_B
#undef RDA
#undef RDB
#undef MMQ
#undef FENCE
#undef BAR
#undef WAIT_LGKM

  // ---- epilogue ----
  const float* bp = bias + (size_t)e * N;
  int cb = n0 + (wc << 6);
  if (MODE == 0) {
#pragma unroll
    for (int mm = 0; mm < 8; mm++) {
#pragma unroll
      for (int j = 0; j < 4; j++) {
        int vr = row0 + (wr << 7) + mm * 16 + (fq << 2) + j;
        int cr = v2c[vr];
        if (cr < 0) continue;
        ushort* hp = h1 + (size_t)cr * N + cb;
#pragma unroll
        for (int nn = 0; nn < 4; nn++) {
          float v = acc[mm][nn][j] + bp[cb + nn * 16 + fr];
          hp[nn * 16 + fr] = f2bf(gelu_t(v));
        }
      }
    }
  } else {
    bool addb = (k0 == 0);
#pragma unroll
    for (int mm = 0; mm < 8; mm++) {
#pragma unroll
      for (int j = 0; j < 4; j++) {
        int vr = row0 + (wr << 7) + mm * 16 + (fq << 2) + j;
        int t2 = tok[vr];
        if (t2 < 0) continue;
        float wgt = wl[vr];
#pragma unroll
        for (int nn = 0; nn < 4; nn++) {
          int c = cb + nn * 16 + fr;
          float v = acc[mm][nn][j] + (addb ? bp[c] : 0.f);
          atomicAdd(&Out[(size_t)t2 * (size_t)N + c], wgt * v);
        }
      }
    }
  }
}

extern "C" void kernel_launch(void* const* d_in, const int* in_sizes, int n_in,
                              void* d_out, int out_size, void* d_ws, size_t ws_size,
                              hipStream_t stream) {
  (void)in_sizes; (void)n_in; (void)out_size; (void)ws_size;
  const float* x    = (const float*)d_in[0];
  const float* bbuf = (const float*)d_in[1];
  const float* Wr   = (const float*)d_in[2];
  const float* br   = (const float*)d_in[3];
  const float* W1   = (const float*)d_in[4];
  const float* b1   = (const float*)d_in[5];
  const float* W2   = (const float*)d_in[6];
  const float* b2   = (const float*)d_in[7];
  float* out = (float*)d_out;

  char* ws = (char*)d_ws;
  ushort* W1T = (ushort*)ws;                          // [E][F][H] bf16  64 MB
  ushort* W2T = (ushort*)(ws + 67108864);             // [E][H][F] bf16  64 MB
  ushort* Xg  = (ushort*)(ws + 134217728);            // [NCOMP][H] bf16 32 MB
  ushort* h1  = (ushort*)(ws + 167772160);            // [NCOMP][F] bf16 128 MB
  char* meta  = ws + 301989888;
  int*   cnt  = (int*)(meta);
  int*   off  = (int*)(meta + 64);
  int*   coff = (int*)(meta + 128);
  int*   cur  = (int*)(meta + 192);
  int*   te   = (int*)(meta + 256);                   // [NTOK*2]
  float* tw   = (float*)(meta + 65792);               // [NTOK*2]
  int*   tok  = (int*)(meta + 131328);                // [VCAP]
  float* wl   = (float*)(meta + 205056);              // [VCAP]
  int*   v2c  = (int*)(meta + 278784);                // [VCAP]
  int*   ctok = (int*)(meta + 352512);                // [NCOMP]

  hipFuncSetAttribute((const void*)&k_gemm<0>,
                      hipFuncAttributeMaxDynamicSharedMemorySize, 131072);
  hipFuncSetAttribute((const void*)&k_gemm<1>,
                      hipFuncAttributeMaxDynamicSharedMemorySize, 131072);

  k_init<<<VMBLK, 256, 0, stream>>>(cnt, cur, tok, wl, v2c);
  k_transcvt<<<dim3(F_ / 64, H_ / 64, E_), 256, 0, stream>>>(W1, W1T, H_, F_);
  k_transcvt<<<dim3(H_ / 64, F_ / 64, E_), 256, 0, stream>>>(W2, W2T, F_, H_);
  k_router<<<NTOK / 4, 256, 0, stream>>>(x, Wr, br, bbuf, cnt, te, tw);
  k_offsets<<<1, 64, 0, stream>>>(cnt, off, coff);
  k_build<<<NTOK / 256, 256, 0, stream>>>(te, tw, off, coff, cur, tok, wl, v2c, ctok);
  k_gather<<<NCOMP, 256, 0, stream>>>(x, ctok, Xg);
  k_zero<<<(NTOK * H_ / 4) / 256, 256, 0, stream>>>(out);
  // GEMM1: M=18432 virt, N=4096 (16 n-tiles of 256), K=1024 (16 K-tiles).
  k_gemm<0><<<16 * VMBLK, 512, 131072, stream>>>(Xg, W1T, b1, h1, nullptr,
                                                 off, v2c, nullptr, nullptr,
                                                 H_, F_, 16);
  // GEMM2: N=1024 (4 n-tiles of 256) x split-K 2, K=4096 (32 K-tiles/split).
  k_gemm<1><<<8 * VMBLK, 512, 131072, stream>>>(h1, W2T, b2, nullptr, out,
                                                off, v2c, tok, wl,
                                                F_, H_, 8);
}

// Round 9
// 996.600 us; speedup vs baseline: 2.2827x; 1.0019x over previous
//
#include <hip/hip_runtime.h>
#include <stdint.h>

#define NTOK 8192
#define H_ 1024
#define F_ 4096
#define E_ 8
#define VCAP 18432      // 16384 slots + up to 8*256 padding (virtual rows)
#define VMBLK 72        // VCAP/256
#define NCOMP 16384     // compact rows (= NTOK * k exactly)

using f32x4  = __attribute__((ext_vector_type(4))) float;
using short8 = __attribute__((ext_vector_type(8))) short;

typedef __attribute__((address_space(1))) const uint32_t gu32;
typedef __attribute__((address_space(3))) uint32_t lu32;

__device__ __forceinline__ void glds16(const void* g, void* l) {
  __builtin_amdgcn_global_load_lds((gu32*)g, (lu32*)l, 16, 0, 0);
}

__device__ __forceinline__ ushort f2bf(float f) {
  union { float f; uint32_t u; } v; v.f = f;
  uint32_t r = (v.u + 0x7FFFu + ((v.u >> 16) & 1u)) >> 16;
  return (ushort)r;
}

__device__ __forceinline__ float gelu_t(float x) {
  float u = 0.7978845608028654f * (x + 0.044715f * x * x * x);
  float e = exp2f(u * 2.885390081777927f);      // exp(2u)
  float th = 1.0f - 2.0f / (1.0f + e);
  return 0.5f * x * (1.0f + th);
}

// ---------------- init ------------------------------------------------------
__global__ void k_init(int* cnt, int* cur, int* tok, float* wl, int* v2c) {
  int i = blockIdx.x * 256 + threadIdx.x;
  if (i < E_) { cnt[i] = 0; cur[i] = 0; }
  if (i < VCAP) { tok[i] = -1; wl[i] = 0.f; v2c[i] = -1; }
}

// ---------------- transpose + fp32->bf16: W[E][R][C] -> WT[E][C][R] ---------
__global__ __launch_bounds__(256) void k_transcvt(const float* __restrict__ W,
                                                  ushort* __restrict__ WT,
                                                  int R, int C) {
  __shared__ float t[64][65];
  int e = blockIdx.z;
  int c0 = blockIdx.x * 64, r0 = blockIdx.y * 64;
  const float* Wp = W + (size_t)e * R * C;
  ushort* Tp = WT + (size_t)e * R * C;
  int tx = threadIdx.x & 15, ty = threadIdx.x >> 4;
#pragma unroll
  for (int i = 0; i < 4; i++) {
    int lr = ty + i * 16;
    const float4 v = *(const float4*)&Wp[(size_t)(r0 + lr) * C + c0 + tx * 4];
    t[lr][tx * 4 + 0] = v.x; t[lr][tx * 4 + 1] = v.y;
    t[lr][tx * 4 + 2] = v.z; t[lr][tx * 4 + 3] = v.w;
  }
  __syncthreads();
#pragma unroll
  for (int i = 0; i < 4; i++) {
    int lc = ty + i * 16;
    ushort4 o;
    o.x = f2bf(t[tx * 4 + 0][lc]);
    o.y = f2bf(t[tx * 4 + 1][lc]);
    o.z = f2bf(t[tx * 4 + 2][lc]);
    o.w = f2bf(t[tx * 4 + 3][lc]);
    *(ushort4*)&Tp[(size_t)(c0 + lc) * R + r0 + tx * 4] = o;
  }
}

// ---------------- router ----------------------------------------------------
__global__ __launch_bounds__(256) void k_router(const float* __restrict__ x,
                                                const float* __restrict__ Wr,
                                                const float* __restrict__ br,
                                                const float* __restrict__ bbuf,
                                                int* cnt, int* te, float* tw) {
  int wid = threadIdx.x >> 6, lane = threadIdx.x & 63;
  int t = blockIdx.x * 4 + wid;
  const float* xp = x + (size_t)t * H_;
  double acc[E_];
#pragma unroll
  for (int e = 0; e < E_; e++) acc[e] = 0.0;
  for (int j = lane; j < H_; j += 64) {
    float xv = xp[j];
    const float4 w0 = *(const float4*)&Wr[j * 8];
    const float4 w1 = *(const float4*)&Wr[j * 8 + 4];
    acc[0] += (double)xv * (double)w0.x;
    acc[1] += (double)xv * (double)w0.y;
    acc[2] += (double)xv * (double)w0.z;
    acc[3] += (double)xv * (double)w0.w;
    acc[4] += (double)xv * (double)w1.x;
    acc[5] += (double)xv * (double)w1.y;
    acc[6] += (double)xv * (double)w1.z;
    acc[7] += (double)xv * (double)w1.w;
  }
#pragma unroll
  for (int e = 0; e < E_; e++)
    for (int s = 32; s > 0; s >>= 1) acc[e] += __shfl_xor(acc[e], s);
  if (lane == 0) {
    double s[E_], m = -1e300;
    for (int e = 0; e < E_; e++) { s[e] = acc[e] + (double)br[e]; if (s[e] > m) m = s[e]; }
    double pe[E_], sum = 0.0;
    for (int e = 0; e < E_; e++) { pe[e] = exp(s[e] - m); sum += pe[e]; }
    double pr[E_], bb[E_];
    for (int e = 0; e < E_; e++) { pr[e] = pe[e] / sum; bb[e] = pr[e] + (double)bbuf[e]; }
    int e0 = 0;
    for (int e = 1; e < E_; e++) if (bb[e] > bb[e0]) e0 = e;
    int e1 = (e0 == 0) ? 1 : 0;
    for (int e = 0; e < E_; e++) if (e != e0 && bb[e] > bb[e1]) e1 = e;
    int a0 = 0;
    for (int e = 1; e < E_; e++) if (pr[e] > pr[a0]) a0 = e;
    int a1 = (a0 == 0) ? 1 : 0;
    for (int e = 0; e < E_; e++) if (e != a0 && pr[e] > pr[a1]) a1 = e;
    double iv = 1.0 / (pr[a0] + pr[a1]);
    te[t * 2] = e0; te[t * 2 + 1] = e1;
    tw[t * 2] = (float)(pr[a0] * iv); tw[t * 2 + 1] = (float)(pr[a1] * iv);
    atomicAdd(&cnt[e0], 1); atomicAdd(&cnt[e1], 1);
  }
}

// ---------------- offsets: 256-padded virtual + compact prefix --------------
__global__ void k_offsets(const int* cnt, int* off, int* coff) {
  if (threadIdx.x == 0 && blockIdx.x == 0) {
    int o = 0, c = 0;
    for (int e = 0; e < E_; e++) {
      off[e] = o; coff[e] = c;
      o += ((cnt[e] + 255) >> 8) << 8;
      c += cnt[e];
    }
    off[E_] = o; coff[E_] = c;
  }
}

// ---------------- build token lists -----------------------------------------
__global__ void k_build(const int* __restrict__ te, const float* __restrict__ tw,
                        const int* __restrict__ off, const int* __restrict__ coff,
                        int* cur, int* tok, float* wl, int* v2c, int* ctok) {
  int t = blockIdx.x * 256 + threadIdx.x;
  if (t >= NTOK) return;
#pragma unroll
  for (int s = 0; s < 2; s++) {
    int e = te[t * 2 + s];
    int slot = atomicAdd(&cur[e], 1);
    int vp = off[e] + slot;
    int cp = coff[e] + slot;
    tok[vp] = t; wl[vp] = tw[t * 2 + s]; v2c[vp] = cp; ctok[cp] = t;
  }
}

// ---------------- gather x rows -> bf16 compact ------------------------------
__global__ __launch_bounds__(256) void k_gather(const float* __restrict__ x,
                                                const int* __restrict__ ctok,
                                                ushort* __restrict__ Xg) {
  int row = blockIdx.x;
  int t = ctok[row];
  const float4* src = (const float4*)(x + (size_t)t * H_);
  ushort4* dst = (ushort4*)(Xg + (size_t)row * H_);
  int i = threadIdx.x;
  float4 v = src[i];
  ushort4 o; o.x = f2bf(v.x); o.y = f2bf(v.y); o.z = f2bf(v.z); o.w = f2bf(v.w);
  dst[i] = o;
}

// ---------------- zero output ------------------------------------------------
__global__ void k_zero(float* out) {
  size_t i = (size_t)blockIdx.x * 256 + threadIdx.x;
  float4 z; z.x = 0.f; z.y = 0.f; z.z = 0.f; z.w = 0.f;
  ((float4*)out)[i] = z;
}

// ---------------- 256x256x64 MFMA GEMM, T3-minimum 2-phase -------------------
// R6-R8: four schedule variants all ~400us -> multi-barrier phase splits were
// the m196 anti-pattern. This round: exact T3 minimum (m230/m248v2 precedent:
// 655-682 TF on grouped 256^2 K=1024). Per tile, ONE vmcnt(0)+barrier:
//   STAGE(T+1 -> other buf) [8 glds16, issued FIRST]
//   16 ds_read (A m0-3 + all B) ; 32 MFMA   (compiler emits fine lgkmcnt)
//    8 ds_read (A m4-7)         ; 32 MFMA
//   vmcnt(0); s_barrier
// Staging flight hides under ~24 ds_read + 64 MFMA. Double buffer makes the
// single barrier sufficient: reads of buf b are register-consumed pre-barrier;
// writes to buf b resume only after it. Swizzle/addressing/epilogue = R8
// (refcheck'd, 0 bank conflicts, no spill).
template <int MODE>
__global__ __launch_bounds__(512) void k_gemm(const ushort* __restrict__ A,
                                              const ushort* __restrict__ BT,
                                              const float* __restrict__ bias,
                                              ushort* __restrict__ h1,
                                              float* __restrict__ Out,
                                              const int* __restrict__ off,
                                              const int* __restrict__ v2c,
                                              const int* __restrict__ tok,
                                              const float* __restrict__ wl,
                                              int K, int N, int NTe) {
  extern __shared__ char lds[];
  // ---- raster: XCD chunk, group-of-4 M, n-id fastest ----
  int nwg = gridDim.x;             // divisible by 8
  int cpx = nwg >> 3;
  int bid = blockIdx.x;
  int lid = (bid & 7) * cpx + (bid >> 3);
  int gsz = NTe << 2;
  int g = lid / gsz, rm = lid % gsz;
  int ne = rm >> 2, m = (g << 2) + (rm & 3);
  int row0 = m << 8;
  if (row0 >= off[E_]) return;
  int e = 0;
  while (off[e + 1] <= row0) e++;
  int n0, k0, nk;
  if (MODE == 0) { n0 = ne << 8; k0 = 0; nk = K >> 6; }
  else           { n0 = (ne >> 1) << 8; k0 = (ne & 1) * (K >> 1); nk = K >> 7; }
  const ushort* Bp = BT + (size_t)e * (size_t)N * (size_t)K;

  int tid = threadIdx.x, lane = tid & 63, w = tid >> 6;
  int wr = w >> 2, wc = w & 3;     // 2 M-halves x 4 N-quarters

  f32x4 acc[8][4];
#pragma unroll
  for (int mm = 0; mm < 8; mm++)
#pragma unroll
    for (int nn = 0; nn < 4; nn++) acc[mm][nn] = (f32x4){0.f, 0.f, 0.f, 0.f};

  // ---- staging addressing: unit = 64 rows x 128 B = 8 KB; thread covers 16 B
  int urow = (w << 3) + (lane >> 3);        // 0..63 row within unit
  int schunk = (lane & 7) ^ (lane >> 3);    // pre-swizzled source chunk
  const char *aS0, *aS1, *aS2, *aS3, *bS0, *bS1, *bS2, *bS3;
  {
    int v0 = v2c[row0 + 0 * 64 + urow];   if (v0 < 0) v0 = 0;
    int v1 = v2c[row0 + 1 * 64 + urow];   if (v1 < 0) v1 = 0;
    int v2 = v2c[row0 + 2 * 64 + urow];   if (v2 < 0) v2 = 0;
    int v3 = v2c[row0 + 3 * 64 + urow];   if (v3 < 0) v3 = 0;
    size_t kb = (size_t)k0 * 2 + (size_t)schunk * 16;
    aS0 = (const char*)(A + (size_t)v0 * K) + kb;
    aS1 = (const char*)(A + (size_t)v1 * K) + kb;
    aS2 = (const char*)(A + (size_t)v2 * K) + kb;
    aS3 = (const char*)(A + (size_t)v3 * K) + kb;
    bS0 = (const char*)(Bp + (size_t)(n0 + 0 * 64 + urow) * K) + kb;
    bS1 = (const char*)(Bp + (size_t)(n0 + 1 * 64 + urow) * K) + kb;
    bS2 = (const char*)(Bp + (size_t)(n0 + 2 * 64 + urow) * K) + kb;
    bS3 = (const char*)(Bp + (size_t)(n0 + 3 * 64 + urow) * K) + kb;
  }

  // ---- fragment read addressing ----
  int fr = lane & 15, fq = lane >> 4;
  int frs = fr & 7;

  short8 af_[4][2], bf_[4][2];

#define STG_A(u, tt, bbuf) glds16(aS##u + (size_t)(tt) * 128, lds + (bbuf) * 65536 + (u) * 8192 + (w << 10))
#define STG_B(u, tt, bbuf) glds16(bS##u + (size_t)(tt) * 128, lds + (bbuf) * 65536 + 32768 + (u) * 8192 + (w << 10))

#define RDA(mmq, bbuf) do {                                                  \
    const ushort* LA_ = (const ushort*)(lds + (bbuf) * 65536);               \
    _Pragma("unroll")                                                        \
    for (int i = 0; i < 4; ++i)                                              \
      _Pragma("unroll")                                                      \
      for (int ks = 0; ks < 2; ++ks)                                         \
        af_[i][ks] = *(const short8*)&LA_[((wr << 7) + ((mmq) + i) * 16 + fr) * 64 + (((ks << 2) + fq) ^ frs) * 8]; \
  } while (0)

#define RDB(bbuf) do {                                                       \
    const ushort* LB_ = (const ushort*)(lds + (bbuf) * 65536 + 32768);       \
    _Pragma("unroll")                                                        \
    for (int i = 0; i < 4; ++i)                                              \
      _Pragma("unroll")                                                      \
      for (int ks = 0; ks < 2; ++ks)                                         \
        bf_[i][ks] = *(const short8*)&LB_[((wc << 6) + i * 16 + fr) * 64 + (((ks << 2) + fq) ^ frs) * 8]; \
  } while (0)

#define MMQ(mmq, nnq) do {                                                   \
    __builtin_amdgcn_s_setprio(1);                                           \
    _Pragma("unroll")                                                        \
    for (int i = 0; i < 4; ++i)                                              \
      _Pragma("unroll")                                                      \
      for (int jn = 0; jn < 2; ++jn)                                         \
        _Pragma("unroll")                                                    \
        for (int ks = 0; ks < 2; ++ks)                                       \
          acc[(mmq) + i][(nnq) + jn] = __builtin_amdgcn_mfma_f32_16x16x32_bf16(af_[i][ks], bf_[(nnq) + jn][ks], acc[(mmq) + i][(nnq) + jn], 0, 0, 0); \
    __builtin_amdgcn_s_setprio(0);                                           \
  } while (0)

#define FENCE() __builtin_amdgcn_sched_barrier(0)
#define BAR()   __builtin_amdgcn_s_barrier()

  // ---- prologue: stage tile 0 -> buf 0, drain, sync ----
  STG_B(0, 0, 0); STG_B(1, 0, 0); STG_B(2, 0, 0); STG_B(3, 0, 0);
  STG_A(0, 0, 0); STG_A(1, 0, 0); STG_A(2, 0, 0); STG_A(3, 0, 0);
  asm volatile("s_waitcnt vmcnt(0)" ::: "memory");
  BAR(); FENCE();

  for (int T = 0; T < nk; ++T) {
    int bb = T & 1, nb = bb ^ 1;
    bool pre = (T + 1 < nk);
    // ---- STAGE next tile first: flight hides under reads+MFMA ----
    if (pre) {
      STG_B(0, T + 1, nb); STG_B(1, T + 1, nb);
      STG_B(2, T + 1, nb); STG_B(3, T + 1, nb);
      STG_A(0, T + 1, nb); STG_A(1, T + 1, nb);
      STG_A(2, T + 1, nb); STG_A(3, T + 1, nb);
    }
    // ---- compute tile T (compiler emits fine-grained lgkmcnt) ----
    RDA(0, bb); RDB(bb);
    MMQ(0, 0); MMQ(0, 2);
    RDA(4, bb);
    MMQ(4, 0); MMQ(4, 2);
    // ---- single drain + barrier per tile ----
    if (pre) {
      asm volatile("s_waitcnt vmcnt(0)" ::: "memory");
      BAR(); FENCE();
    }
  }
#undef STG_A
#undef STG_B
#undef RDA
#undef RDB
#undef MMQ
#undef FENCE
#undef BAR

  // ---- epilogue ----
  const float* bp = bias + (size_t)e * N;
  int cb = n0 + (wc << 6);
  if (MODE == 0) {
#pragma unroll
    for (int mm = 0; mm < 8; mm++) {
#pragma unroll
      for (int j = 0; j < 4; j++) {
        int vr = row0 + (wr << 7) + mm * 16 + (fq << 2) + j;
        int cr = v2c[vr];
        if (cr < 0) continue;
        ushort* hp = h1 + (size_t)cr * N + cb;
#pragma unroll
        for (int nn = 0; nn < 4; nn++) {
          float v = acc[mm][nn][j] + bp[cb + nn * 16 + fr];
          hp[nn * 16 + fr] = f2bf(gelu_t(v));
        }
      }
    }
  } else {
    bool addb = (k0 == 0);
#pragma unroll
    for (int mm = 0; mm < 8; mm++) {
#pragma unroll
      for (int j = 0; j < 4; j++) {
        int vr = row0 + (wr << 7) + mm * 16 + (fq << 2) + j;
        int t2 = tok[vr];
        if (t2 < 0) continue;
        float wgt = wl[vr];
#pragma unroll
        for (int nn = 0; nn < 4; nn++) {
          int c = cb + nn * 16 + fr;
          float v = acc[mm][nn][j] + (addb ? bp[c] : 0.f);
          atomicAdd(&Out[(size_t)t2 * (size_t)N + c], wgt * v);
        }
      }
    }
  }
}

extern "C" void kernel_launch(void* const* d_in, const int* in_sizes, int n_in,
                              void* d_out, int out_size, void* d_ws, size_t ws_size,
                              hipStream_t stream) {
  (void)in_sizes; (void)n_in; (void)out_size; (void)ws_size;
  const float* x    = (const float*)d_in[0];
  const float* bbuf = (const float*)d_in[1];
  const float* Wr   = (const float*)d_in[2];
  const float* br   = (const float*)d_in[3];
  const float* W1   = (const float*)d_in[4];
  const float* b1   = (const float*)d_in[5];
  const float* W2   = (const float*)d_in[6];
  const float* b2   = (const float*)d_in[7];
  float* out = (float*)d_out;

  char* ws = (char*)d_ws;
  ushort* W1T = (ushort*)ws;                          // [E][F][H] bf16  64 MB
  ushort* W2T = (ushort*)(ws + 67108864);             // [E][H][F] bf16  64 MB
  ushort* Xg  = (ushort*)(ws + 134217728);            // [NCOMP][H] bf16 32 MB
  ushort* h1  = (ushort*)(ws + 167772160);            // [NCOMP][F] bf16 128 MB
  char* meta  = ws + 301989888;
  int*   cnt  = (int*)(meta);
  int*   off  = (int*)(meta + 64);
  int*   coff = (int*)(meta + 128);
  int*   cur  = (int*)(meta + 192);
  int*   te   = (int*)(meta + 256);                   // [NTOK*2]
  float* tw   = (float*)(meta + 65792);               // [NTOK*2]
  int*   tok  = (int*)(meta + 131328);                // [VCAP]
  float* wl   = (float*)(meta + 205056);              // [VCAP]
  int*   v2c  = (int*)(meta + 278784);                // [VCAP]
  int*   ctok = (int*)(meta + 352512);                // [NCOMP]

  hipFuncSetAttribute((const void*)&k_gemm<0>,
                      hipFuncAttributeMaxDynamicSharedMemorySize, 131072);
  hipFuncSetAttribute((const void*)&k_gemm<1>,
                      hipFuncAttributeMaxDynamicSharedMemorySize, 131072);

  k_init<<<VMBLK, 256, 0, stream>>>(cnt, cur, tok, wl, v2c);
  k_transcvt<<<dim3(F_ / 64, H_ / 64, E_), 256, 0, stream>>>(W1, W1T, H_, F_);
  k_transcvt<<<dim3(H_ / 64, F_ / 64, E_), 256, 0, stream>>>(W2, W2T, F_, H_);
  k_router<<<NTOK / 4, 256, 0, stream>>>(x, Wr, br, bbuf, cnt, te, tw);
  k_offsets<<<1, 64, 0, stream>>>(cnt, off, coff);
  k_build<<<NTOK / 256, 256, 0, stream>>>(te, tw, off, coff, cur, tok, wl, v2c, ctok);
  k_gather<<<NCOMP, 256, 0, stream>>>(x, ctok, Xg);
  k_zero<<<(NTOK * H_ / 4) / 256, 256, 0, stream>>>(out);
  // GEMM1: M=18432 virt, N=4096 (16 n-tiles of 256), K=1024 (16 K-tiles).
  k_gemm<0><<<16 * VMBLK, 512, 131072, stream>>>(Xg, W1T, b1, h1, nullptr,
                                                 off, v2c, nullptr, nullptr,
                                                 H_, F_, 16);
  // GEMM2: N=1024 (4 n-tiles of 256) x split-K 2, K=4096 (32 K-tiles/split).
  k_gemm<1><<<8 * VMBLK, 512, 131072, stream>>>(h1, W2T, b2, nullptr, out,
                                                off, v2c, tok, wl,
                                                F_, H_, 8);
}

// Round 10
// 892.851 us; speedup vs baseline: 2.5479x; 1.1162x over previous
//
#include <hip/hip_runtime.h>
#include <stdint.h>

#define NTOK 8192
#define H_ 1024
#define F_ 4096
#define E_ 8
#define VCAP 18432      // 16384 slots + up to 8*256 padding (virtual rows)
#define VMBLK 72        // VCAP/256
#define MT 144          // VCAP/128 M-tiles for the 128-row GEMM rasters
#define NCOMP 16384     // compact rows (= NTOK * k exactly)

using f32x4  = __attribute__((ext_vector_type(4))) float;
using short8 = __attribute__((ext_vector_type(8))) short;

typedef __attribute__((address_space(1))) const uint32_t gu32;
typedef __attribute__((address_space(3))) uint32_t lu32;

__device__ __forceinline__ void glds16(const void* g, void* l) {
  __builtin_amdgcn_global_load_lds((gu32*)g, (lu32*)l, 16, 0, 0);
}

__device__ __forceinline__ ushort f2bf(float f) {
  union { float f; uint32_t u; } v; v.f = f;
  uint32_t r = (v.u + 0x7FFFu + ((v.u >> 16) & 1u)) >> 16;
  return (ushort)r;
}

__device__ __forceinline__ float gelu_t(float x) {
  float u = 0.7978845608028654f * (x + 0.044715f * x * x * x);
  float e = exp2f(u * 2.885390081777927f);      // exp(2u)
  float th = 1.0f - 2.0f / (1.0f + e);
  return 0.5f * x * (1.0f + th);
}

// ---------------- init ------------------------------------------------------
__global__ void k_init(int* cnt, int* cur, int* tok, float* wl, int* v2c) {
  int i = blockIdx.x * 256 + threadIdx.x;
  if (i < E_) { cnt[i] = 0; cur[i] = 0; }
  if (i < VCAP) { tok[i] = -1; wl[i] = 0.f; v2c[i] = -1; }
}

// ---------------- transpose + fp32->bf16: W[E][R][C] -> WT[E][C][R] ---------
__global__ __launch_bounds__(256) void k_transcvt(const float* __restrict__ W,
                                                  ushort* __restrict__ WT,
                                                  int R, int C) {
  __shared__ float t[64][65];
  int e = blockIdx.z;
  int c0 = blockIdx.x * 64, r0 = blockIdx.y * 64;
  const float* Wp = W + (size_t)e * R * C;
  ushort* Tp = WT + (size_t)e * R * C;
  int tx = threadIdx.x & 15, ty = threadIdx.x >> 4;
#pragma unroll
  for (int i = 0; i < 4; i++) {
    int lr = ty + i * 16;
    const float4 v = *(const float4*)&Wp[(size_t)(r0 + lr) * C + c0 + tx * 4];
    t[lr][tx * 4 + 0] = v.x; t[lr][tx * 4 + 1] = v.y;
    t[lr][tx * 4 + 2] = v.z; t[lr][tx * 4 + 3] = v.w;
  }
  __syncthreads();
#pragma unroll
  for (int i = 0; i < 4; i++) {
    int lc = ty + i * 16;
    ushort4 o;
    o.x = f2bf(t[tx * 4 + 0][lc]);
    o.y = f2bf(t[tx * 4 + 1][lc]);
    o.z = f2bf(t[tx * 4 + 2][lc]);
    o.w = f2bf(t[tx * 4 + 3][lc]);
    *(ushort4*)&Tp[(size_t)(c0 + lc) * R + r0 + tx * 4] = o;
  }
}

// ---------------- router ----------------------------------------------------
__global__ __launch_bounds__(256) void k_router(const float* __restrict__ x,
                                                const float* __restrict__ Wr,
                                                const float* __restrict__ br,
                                                const float* __restrict__ bbuf,
                                                int* cnt, int* te, float* tw) {
  int wid = threadIdx.x >> 6, lane = threadIdx.x & 63;
  int t = blockIdx.x * 4 + wid;
  const float* xp = x + (size_t)t * H_;
  double acc[E_];
#pragma unroll
  for (int e = 0; e < E_; e++) acc[e] = 0.0;
  for (int j = lane; j < H_; j += 64) {
    float xv = xp[j];
    const float4 w0 = *(const float4*)&Wr[j * 8];
    const float4 w1 = *(const float4*)&Wr[j * 8 + 4];
    acc[0] += (double)xv * (double)w0.x;
    acc[1] += (double)xv * (double)w0.y;
    acc[2] += (double)xv * (double)w0.z;
    acc[3] += (double)xv * (double)w0.w;
    acc[4] += (double)xv * (double)w1.x;
    acc[5] += (double)xv * (double)w1.y;
    acc[6] += (double)xv * (double)w1.z;
    acc[7] += (double)xv * (double)w1.w;
  }
#pragma unroll
  for (int e = 0; e < E_; e++)
    for (int s = 32; s > 0; s >>= 1) acc[e] += __shfl_xor(acc[e], s);
  if (lane == 0) {
    double s[E_], m = -1e300;
    for (int e = 0; e < E_; e++) { s[e] = acc[e] + (double)br[e]; if (s[e] > m) m = s[e]; }
    double pe[E_], sum = 0.0;
    for (int e = 0; e < E_; e++) { pe[e] = exp(s[e] - m); sum += pe[e]; }
    double pr[E_], bb[E_];
    for (int e = 0; e < E_; e++) { pr[e] = pe[e] / sum; bb[e] = pr[e] + (double)bbuf[e]; }
    int e0 = 0;
    for (int e = 1; e < E_; e++) if (bb[e] > bb[e0]) e0 = e;
    int e1 = (e0 == 0) ? 1 : 0;
    for (int e = 0; e < E_; e++) if (e != e0 && bb[e] > bb[e1]) e1 = e;
    int a0 = 0;
    for (int e = 1; e < E_; e++) if (pr[e] > pr[a0]) a0 = e;
    int a1 = (a0 == 0) ? 1 : 0;
    for (int e = 0; e < E_; e++) if (e != a0 && pr[e] > pr[a1]) a1 = e;
    double iv = 1.0 / (pr[a0] + pr[a1]);
    te[t * 2] = e0; te[t * 2 + 1] = e1;
    tw[t * 2] = (float)(pr[a0] * iv); tw[t * 2 + 1] = (float)(pr[a1] * iv);
    atomicAdd(&cnt[e0], 1); atomicAdd(&cnt[e1], 1);
  }
}

// ---------------- offsets: 256-padded virtual + compact prefix --------------
__global__ void k_offsets(const int* cnt, int* off, int* coff) {
  if (threadIdx.x == 0 && blockIdx.x == 0) {
    int o = 0, c = 0;
    for (int e = 0; e < E_; e++) {
      off[e] = o; coff[e] = c;
      o += ((cnt[e] + 255) >> 8) << 8;
      c += cnt[e];
    }
    off[E_] = o; coff[E_] = c;
  }
}

// ---------------- build token lists -----------------------------------------
__global__ void k_build(const int* __restrict__ te, const float* __restrict__ tw,
                        const int* __restrict__ off, const int* __restrict__ coff,
                        int* cur, int* tok, float* wl, int* v2c, int* ctok) {
  int t = blockIdx.x * 256 + threadIdx.x;
  if (t >= NTOK) return;
#pragma unroll
  for (int s = 0; s < 2; s++) {
    int e = te[t * 2 + s];
    int slot = atomicAdd(&cur[e], 1);
    int vp = off[e] + slot;
    int cp = coff[e] + slot;
    tok[vp] = t; wl[vp] = tw[t * 2 + s]; v2c[vp] = cp; ctok[cp] = t;
  }
}

// ---------------- gather x rows -> bf16 compact ------------------------------
__global__ __launch_bounds__(256) void k_gather(const float* __restrict__ x,
                                                const int* __restrict__ ctok,
                                                ushort* __restrict__ Xg) {
  int row = blockIdx.x;
  int t = ctok[row];
  const float4* src = (const float4*)(x + (size_t)t * H_);
  ushort4* dst = (ushort4*)(Xg + (size_t)row * H_);
  int i = threadIdx.x;
  float4 v = src[i];
  ushort4 o; o.x = f2bf(v.x); o.y = f2bf(v.y); o.z = f2bf(v.z); o.w = f2bf(v.w);
  dst[i] = o;
}

// ---------------- zero output ------------------------------------------------
__global__ void k_zero(float* out) {
  size_t i = (size_t)blockIdx.x * 256 + threadIdx.x;
  float4 z; z.x = 0.f; z.y = 0.f; z.z = 0.f; z.w = 0.f;
  ((float4*)out)[i] = z;
}

// ---------------- 128x128x64 MFMA GEMM, m97-style, 3 blocks/CU ---------------
// R4-R9 post-mortem: 128KB LDS + 232 regs/wave -> 1 block/CU, 8 lockstep
// waves; every barrier/latency stall fully exposed; 5 schedule variants all
// ~396us (MfmaUtil 15%). This round restores TLP (the m97/m114 mechanism:
// co-resident blocks hide each other's barrier drains):
//   tile 128x128, BK=64, SINGLE-buffer LDS 32 KB, 256 thr (4 waves),
//   wave tile 64x64 (acc[4][4]=64 AGPR), per-ks frag reads (32 live frag regs)
//   -> ~140 regs/wave, __launch_bounds__(256,3): 12 waves/CU = 3 blocks/CU.
// Loop = m97's plain 2-syncthreads form (874 TF precedent; no asm/fences).
// Swizzle = R7-verified (0 conflicts): LDS[r][c]=G[r][c^(r&7)], pre-swizzled
// glds source + XOR'd frag read chunk.
// Raster: XCD chunk, n-group-of-4 outer (B-panel L2-resident), m fastest.
// MODE 0: h1[v2c[row]] = gelu(A@B + b1[e]).  MODE 1: atomicAdd into Out.
template <int MODE>
__global__ __launch_bounds__(256, 3) void k_gemm(const ushort* __restrict__ A,
                                                 const ushort* __restrict__ BT,
                                                 const float* __restrict__ bias,
                                                 ushort* __restrict__ h1,
                                                 float* __restrict__ Out,
                                                 const int* __restrict__ off,
                                                 const int* __restrict__ v2c,
                                                 const int* __restrict__ tok,
                                                 const float* __restrict__ wl,
                                                 int K, int N, int NTe) {
  __shared__ __align__(16) ushort As[128 * 64];   // 16 KB
  __shared__ __align__(16) ushort Bs[128 * 64];   // 16 KB

  // ---- raster: XCD chunk; within: n-group-of-4 outer, m fastest ----
  int nwg = gridDim.x;             // divisible by 8
  int cpx = nwg >> 3;
  int bid = blockIdx.x;
  int lid = (bid & 7) * cpx + (bid >> 3);
  int ng = lid / (MT * 4), r = lid % (MT * 4);
  int m = r >> 2;
  int ne = (ng << 2) + (r & 3);
  int row0 = m << 7;
  if (row0 >= off[E_]) return;
  int e = 0;
  while (off[e + 1] <= row0) e++;
  int n0, k0, nk;
  if (MODE == 0) { n0 = ne << 7; k0 = 0; nk = K >> 6; }
  else           { n0 = (ne >> 1) << 7; k0 = (ne & 1) * (K >> 1); nk = K >> 7; }
  const ushort* Bp = BT + (size_t)e * (size_t)N * (size_t)K;

  int tid = threadIdx.x, lane = tid & 63, w = tid >> 6;
  int wr = w >> 1, wc = w & 1;     // 2x2 wave grid, wave tile 64x64

  f32x4 acc[4][4];
#pragma unroll
  for (int mm = 0; mm < 4; mm++)
#pragma unroll
    for (int nn = 0; nn < 4; nn++) acc[mm][nn] = (f32x4){0.f, 0.f, 0.f, 0.f};

  // ---- staging: linear chunk idx = j*256 + w*64 + lane; row = idx>>3 ----
  // row = j*32 + urow, urow = w*8 + lane>>3 (0..31); chunk c = lane&7.
  // Source pre-swizzled: src chunk = c ^ (row&7) = c ^ (urow&7).
  int urow = (w << 3) + (lane >> 3);
  int sc = (lane & 7) ^ (urow & 7);
  const char *aP0, *aP1, *aP2, *aP3, *bP0, *bP1, *bP2, *bP3;
  {
    size_t kb = (size_t)k0 * 2 + (size_t)sc * 16;
    int c0 = v2c[row0 + 0 * 32 + urow];  if (c0 < 0) c0 = 0;
    int c1 = v2c[row0 + 1 * 32 + urow];  if (c1 < 0) c1 = 0;
    int c2 = v2c[row0 + 2 * 32 + urow];  if (c2 < 0) c2 = 0;
    int c3 = v2c[row0 + 3 * 32 + urow];  if (c3 < 0) c3 = 0;
    aP0 = (const char*)(A + (size_t)c0 * K) + kb;
    aP1 = (const char*)(A + (size_t)c1 * K) + kb;
    aP2 = (const char*)(A + (size_t)c2 * K) + kb;
    aP3 = (const char*)(A + (size_t)c3 * K) + kb;
    bP0 = (const char*)(Bp + (size_t)(n0 + 0 * 32 + urow) * K) + kb;
    bP1 = (const char*)(Bp + (size_t)(n0 + 1 * 32 + urow) * K) + kb;
    bP2 = (const char*)(Bp + (size_t)(n0 + 2 * 32 + urow) * K) + kb;
    bP3 = (const char*)(Bp + (size_t)(n0 + 3 * 32 + urow) * K) + kb;
  }

  // ---- fragment read addressing (swizzled) ----
  int fr = lane & 15, fq = lane >> 4;
  int frs = fr & 7;

  for (int kk = 0; kk < nk; ++kk) {
    size_t kbo = (size_t)kk * 128;      // 64 elems * 2 B
    if (kk) __syncthreads();            // prior tile's reads complete
    glds16(aP0 + kbo, (char*)As + 0 * 4096 + (w << 10));
    glds16(bP0 + kbo, (char*)Bs + 0 * 4096 + (w << 10));
    glds16(aP1 + kbo, (char*)As + 1 * 4096 + (w << 10));
    glds16(bP1 + kbo, (char*)Bs + 1 * 4096 + (w << 10));
    glds16(aP2 + kbo, (char*)As + 2 * 4096 + (w << 10));
    glds16(bP2 + kbo, (char*)Bs + 2 * 4096 + (w << 10));
    glds16(aP3 + kbo, (char*)As + 3 * 4096 + (w << 10));
    glds16(bP3 + kbo, (char*)Bs + 3 * 4096 + (w << 10));
    __syncthreads();                    // drains vmcnt(0): tile visible
#pragma unroll
    for (int ks = 0; ks < 2; ++ks) {
      short8 af[4], bf[4];
      int kc = (((ks << 2) + fq) ^ frs) << 3;
#pragma unroll
      for (int i = 0; i < 4; ++i)
        af[i] = *(const short8*)&As[((wr << 6) + i * 16 + fr) * 64 + kc];
#pragma unroll
      for (int i = 0; i < 4; ++i)
        bf[i] = *(const short8*)&Bs[((wc << 6) + i * 16 + fr) * 64 + kc];
#pragma unroll
      for (int mm = 0; mm < 4; ++mm)
#pragma unroll
        for (int nn = 0; nn < 4; ++nn)
          acc[mm][nn] = __builtin_amdgcn_mfma_f32_16x16x32_bf16(af[mm], bf[nn], acc[mm][nn], 0, 0, 0);
    }
  }

  // ---- epilogue ----
  const float* bp = bias + (size_t)e * N;
  int cb = n0 + (wc << 6);
  if (MODE == 0) {
#pragma unroll
    for (int mm = 0; mm < 4; mm++) {
#pragma unroll
      for (int j = 0; j < 4; j++) {
        int vr = row0 + (wr << 6) + mm * 16 + (fq << 2) + j;
        int cr = v2c[vr];
        if (cr < 0) continue;
        ushort* hp = h1 + (size_t)cr * N + cb;
#pragma unroll
        for (int nn = 0; nn < 4; nn++) {
          float v = acc[mm][nn][j] + bp[cb + nn * 16 + fr];
          hp[nn * 16 + fr] = f2bf(gelu_t(v));
        }
      }
    }
  } else {
    bool addb = (k0 == 0);
#pragma unroll
    for (int mm = 0; mm < 4; mm++) {
#pragma unroll
      for (int j = 0; j < 4; j++) {
        int vr = row0 + (wr << 6) + mm * 16 + (fq << 2) + j;
        int t2 = tok[vr];
        if (t2 < 0) continue;
        float wgt = wl[vr];
#pragma unroll
        for (int nn = 0; nn < 4; nn++) {
          int c = cb + nn * 16 + fr;
          float v = acc[mm][nn][j] + (addb ? bp[c] : 0.f);
          atomicAdd(&Out[(size_t)t2 * (size_t)N + c], wgt * v);
        }
      }
    }
  }
}

extern "C" void kernel_launch(void* const* d_in, const int* in_sizes, int n_in,
                              void* d_out, int out_size, void* d_ws, size_t ws_size,
                              hipStream_t stream) {
  (void)in_sizes; (void)n_in; (void)out_size; (void)ws_size;
  const float* x    = (const float*)d_in[0];
  const float* bbuf = (const float*)d_in[1];
  const float* Wr   = (const float*)d_in[2];
  const float* br   = (const float*)d_in[3];
  const float* W1   = (const float*)d_in[4];
  const float* b1   = (const float*)d_in[5];
  const float* W2   = (const float*)d_in[6];
  const float* b2   = (const float*)d_in[7];
  float* out = (float*)d_out;

  char* ws = (char*)d_ws;
  ushort* W1T = (ushort*)ws;                          // [E][F][H] bf16  64 MB
  ushort* W2T = (ushort*)(ws + 67108864);             // [E][H][F] bf16  64 MB
  ushort* Xg  = (ushort*)(ws + 134217728);            // [NCOMP][H] bf16 32 MB
  ushort* h1  = (ushort*)(ws + 167772160);            // [NCOMP][F] bf16 128 MB
  char* meta  = ws + 301989888;
  int*   cnt  = (int*)(meta);
  int*   off  = (int*)(meta + 64);
  int*   coff = (int*)(meta + 128);
  int*   cur  = (int*)(meta + 192);
  int*   te   = (int*)(meta + 256);                   // [NTOK*2]
  float* tw   = (float*)(meta + 65792);               // [NTOK*2]
  int*   tok  = (int*)(meta + 131328);                // [VCAP]
  float* wl   = (float*)(meta + 205056);              // [VCAP]
  int*   v2c  = (int*)(meta + 278784);                // [VCAP]
  int*   ctok = (int*)(meta + 352512);                // [NCOMP]

  k_init<<<VMBLK, 256, 0, stream>>>(cnt, cur, tok, wl, v2c);
  k_transcvt<<<dim3(F_ / 64, H_ / 64, E_), 256, 0, stream>>>(W1, W1T, H_, F_);
  k_transcvt<<<dim3(H_ / 64, F_ / 64, E_), 256, 0, stream>>>(W2, W2T, F_, H_);
  k_router<<<NTOK / 4, 256, 0, stream>>>(x, Wr, br, bbuf, cnt, te, tw);
  k_offsets<<<1, 64, 0, stream>>>(cnt, off, coff);
  k_build<<<NTOK / 256, 256, 0, stream>>>(te, tw, off, coff, cur, tok, wl, v2c, ctok);
  k_gather<<<NCOMP, 256, 0, stream>>>(x, ctok, Xg);
  k_zero<<<(NTOK * H_ / 4) / 256, 256, 0, stream>>>(out);
  // GEMM1: M=18432 virt (144 m-tiles), N=4096 (32 n-tiles of 128), K=1024.
  k_gemm<0><<<32 * MT, 256, 0, stream>>>(Xg, W1T, b1, h1, nullptr,
                                         off, v2c, nullptr, nullptr,
                                         H_, F_, 32);
  // GEMM2: N=1024 (8 n-tiles of 128) x split-K 2 -> ne=16; K=4096.
  k_gemm<1><<<16 * MT, 256, 0, stream>>>(h1, W2T, b2, nullptr, out,
                                         off, v2c, tok, wl,
                                         F_, H_, 16);
}

// Round 11
// 887.933 us; speedup vs baseline: 2.5621x; 1.0055x over previous
//
#include <hip/hip_runtime.h>
#include <stdint.h>

#define NTOK 8192
#define H_ 1024
#define F_ 4096
#define E_ 8
#define VCAP 18432      // 16384 slots + up to 8*256 padding (virtual rows)
#define VMBLK 72        // VCAP/256
#define MT 144          // VCAP/128 M-tiles for the 128-row GEMM rasters
#define NCOMP 16384     // compact rows (= NTOK * k exactly)

using f32x4  = __attribute__((ext_vector_type(4))) float;
using short8 = __attribute__((ext_vector_type(8))) short;

typedef __attribute__((address_space(1))) const uint32_t gu32;
typedef __attribute__((address_space(3))) uint32_t lu32;

__device__ __forceinline__ void glds16(const void* g, void* l) {
  __builtin_amdgcn_global_load_lds((gu32*)g, (lu32*)l, 16, 0, 0);
}

__device__ __forceinline__ ushort f2bf(float f) {
  union { float f; uint32_t u; } v; v.f = f;
  uint32_t r = (v.u + 0x7FFFu + ((v.u >> 16) & 1u)) >> 16;
  return (ushort)r;
}

__device__ __forceinline__ float gelu_t(float x) {
  float u = 0.7978845608028654f * (x + 0.044715f * x * x * x);
  float e = exp2f(u * 2.885390081777927f);      // exp(2u)
  float th = 1.0f - 2.0f / (1.0f + e);
  return 0.5f * x * (1.0f + th);
}

// ---------------- init ------------------------------------------------------
__global__ void k_init(int* cnt, int* cur, int* tok, float* wl, int* v2c) {
  int i = blockIdx.x * 256 + threadIdx.x;
  if (i < E_) { cnt[i] = 0; cur[i] = 0; }
  if (i < VCAP) { tok[i] = -1; wl[i] = 0.f; v2c[i] = -1; }
}

// ---------------- transpose + fp32->bf16: W[E][R][C] -> WT[E][C][R] ---------
__global__ __launch_bounds__(256) void k_transcvt(const float* __restrict__ W,
                                                  ushort* __restrict__ WT,
                                                  int R, int C) {
  __shared__ float t[64][65];
  int e = blockIdx.z;
  int c0 = blockIdx.x * 64, r0 = blockIdx.y * 64;
  const float* Wp = W + (size_t)e * R * C;
  ushort* Tp = WT + (size_t)e * R * C;
  int tx = threadIdx.x & 15, ty = threadIdx.x >> 4;
#pragma unroll
  for (int i = 0; i < 4; i++) {
    int lr = ty + i * 16;
    const float4 v = *(const float4*)&Wp[(size_t)(r0 + lr) * C + c0 + tx * 4];
    t[lr][tx * 4 + 0] = v.x; t[lr][tx * 4 + 1] = v.y;
    t[lr][tx * 4 + 2] = v.z; t[lr][tx * 4 + 3] = v.w;
  }
  __syncthreads();
#pragma unroll
  for (int i = 0; i < 4; i++) {
    int lc = ty + i * 16;
    ushort4 o;
    o.x = f2bf(t[tx * 4 + 0][lc]);
    o.y = f2bf(t[tx * 4 + 1][lc]);
    o.z = f2bf(t[tx * 4 + 2][lc]);
    o.w = f2bf(t[tx * 4 + 3][lc]);
    *(ushort4*)&Tp[(size_t)(c0 + lc) * R + r0 + tx * 4] = o;
  }
}

// ---------------- router ----------------------------------------------------
__global__ __launch_bounds__(256) void k_router(const float* __restrict__ x,
                                                const float* __restrict__ Wr,
                                                const float* __restrict__ br,
                                                const float* __restrict__ bbuf,
                                                int* cnt, int* te, float* tw) {
  int wid = threadIdx.x >> 6, lane = threadIdx.x & 63;
  int t = blockIdx.x * 4 + wid;
  const float* xp = x + (size_t)t * H_;
  double acc[E_];
#pragma unroll
  for (int e = 0; e < E_; e++) acc[e] = 0.0;
  for (int j = lane; j < H_; j += 64) {
    float xv = xp[j];
    const float4 w0 = *(const float4*)&Wr[j * 8];
    const float4 w1 = *(const float4*)&Wr[j * 8 + 4];
    acc[0] += (double)xv * (double)w0.x;
    acc[1] += (double)xv * (double)w0.y;
    acc[2] += (double)xv * (double)w0.z;
    acc[3] += (double)xv * (double)w0.w;
    acc[4] += (double)xv * (double)w1.x;
    acc[5] += (double)xv * (double)w1.y;
    acc[6] += (double)xv * (double)w1.z;
    acc[7] += (double)xv * (double)w1.w;
  }
#pragma unroll
  for (int e = 0; e < E_; e++)
    for (int s = 32; s > 0; s >>= 1) acc[e] += __shfl_xor(acc[e], s);
  if (lane == 0) {
    double s[E_], m = -1e300;
    for (int e = 0; e < E_; e++) { s[e] = acc[e] + (double)br[e]; if (s[e] > m) m = s[e]; }
    double pe[E_], sum = 0.0;
    for (int e = 0; e < E_; e++) { pe[e] = exp(s[e] - m); sum += pe[e]; }
    double pr[E_], bb[E_];
    for (int e = 0; e < E_; e++) { pr[e] = pe[e] / sum; bb[e] = pr[e] + (double)bbuf[e]; }
    int e0 = 0;
    for (int e = 1; e < E_; e++) if (bb[e] > bb[e0]) e0 = e;
    int e1 = (e0 == 0) ? 1 : 0;
    for (int e = 0; e < E_; e++) if (e != e0 && bb[e] > bb[e1]) e1 = e;
    int a0 = 0;
    for (int e = 1; e < E_; e++) if (pr[e] > pr[a0]) a0 = e;
    int a1 = (a0 == 0) ? 1 : 0;
    for (int e = 0; e < E_; e++) if (e != a0 && pr[e] > pr[a1]) a1 = e;
    double iv = 1.0 / (pr[a0] + pr[a1]);
    te[t * 2] = e0; te[t * 2 + 1] = e1;
    tw[t * 2] = (float)(pr[a0] * iv); tw[t * 2 + 1] = (float)(pr[a1] * iv);
    atomicAdd(&cnt[e0], 1); atomicAdd(&cnt[e1], 1);
  }
}

// ---------------- offsets: 256-padded virtual + compact prefix --------------
__global__ void k_offsets(const int* cnt, int* off, int* coff) {
  if (threadIdx.x == 0 && blockIdx.x == 0) {
    int o = 0, c = 0;
    for (int e = 0; e < E_; e++) {
      off[e] = o; coff[e] = c;
      o += ((cnt[e] + 255) >> 8) << 8;
      c += cnt[e];
    }
    off[E_] = o; coff[E_] = c;
  }
}

// ---------------- build token lists -----------------------------------------
__global__ void k_build(const int* __restrict__ te, const float* __restrict__ tw,
                        const int* __restrict__ off, const int* __restrict__ coff,
                        int* cur, int* tok, float* wl, int* v2c, int* ctok) {
  int t = blockIdx.x * 256 + threadIdx.x;
  if (t >= NTOK) return;
#pragma unroll
  for (int s = 0; s < 2; s++) {
    int e = te[t * 2 + s];
    int slot = atomicAdd(&cur[e], 1);
    int vp = off[e] + slot;
    int cp = coff[e] + slot;
    tok[vp] = t; wl[vp] = tw[t * 2 + s]; v2c[vp] = cp; ctok[cp] = t;
  }
}

// ---------------- gather x rows -> bf16 compact ------------------------------
__global__ __launch_bounds__(256) void k_gather(const float* __restrict__ x,
                                                const int* __restrict__ ctok,
                                                ushort* __restrict__ Xg) {
  int row = blockIdx.x;
  int t = ctok[row];
  const float4* src = (const float4*)(x + (size_t)t * H_);
  ushort4* dst = (ushort4*)(Xg + (size_t)row * H_);
  int i = threadIdx.x;
  float4 v = src[i];
  ushort4 o; o.x = f2bf(v.x); o.y = f2bf(v.y); o.z = f2bf(v.z); o.w = f2bf(v.w);
  dst[i] = o;
}

// ---------------- zero output ------------------------------------------------
__global__ void k_zero(float* out) {
  size_t i = (size_t)blockIdx.x * 256 + threadIdx.x;
  float4 z; z.x = 0.f; z.y = 0.f; z.z = 0.f; z.w = 0.f;
  ((float4*)out)[i] = z;
}

// ---------------- 128x128x64 MFMA GEMM, m97-style, 4 blocks/CU ---------------
// R10 confirmed the occupancy mechanism: (256,3) -> 2.5 blocks/CU, 396->296us,
// MfmaUtil 15->20.5. This round: (256,4) -> 16 waves/CU = 4 blocks/CU.
// Reg budget 128/wave unified: acc 64 AGPR + in-loop arch ~64 (frags 32,
// 8 ptr-pairs 16, loop ~10, lane consts ~6) - fits; epilogue overflow would
// be cold spill only. Everything else identical to R10 (refcheck'd, 0 bank
// conflicts): single-buffer 32KB LDS, 2-syncthreads loop, verified swizzle,
// XCD chunk + n-group-of-4 outer raster.
// MODE 0: h1[v2c[row]] = gelu(A@B + b1[e]).  MODE 1: atomicAdd into Out.
template <int MODE>
__global__ __launch_bounds__(256, 4) void k_gemm(const ushort* __restrict__ A,
                                                 const ushort* __restrict__ BT,
                                                 const float* __restrict__ bias,
                                                 ushort* __restrict__ h1,
                                                 float* __restrict__ Out,
                                                 const int* __restrict__ off,
                                                 const int* __restrict__ v2c,
                                                 const int* __restrict__ tok,
                                                 const float* __restrict__ wl,
                                                 int K, int N, int NTe) {
  __shared__ __align__(16) ushort As[128 * 64];   // 16 KB
  __shared__ __align__(16) ushort Bs[128 * 64];   // 16 KB

  // ---- raster: XCD chunk; within: n-group-of-4 outer, m fastest ----
  int nwg = gridDim.x;             // divisible by 8
  int cpx = nwg >> 3;
  int bid = blockIdx.x;
  int lid = (bid & 7) * cpx + (bid >> 3);
  int ng = lid / (MT * 4), r = lid % (MT * 4);
  int m = r >> 2;
  int ne = (ng << 2) + (r & 3);
  int row0 = m << 7;
  if (row0 >= off[E_]) return;
  int e = 0;
  while (off[e + 1] <= row0) e++;
  int n0, k0, nk;
  if (MODE == 0) { n0 = ne << 7; k0 = 0; nk = K >> 6; }
  else           { n0 = (ne >> 1) << 7; k0 = (ne & 1) * (K >> 1); nk = K >> 7; }
  const ushort* Bp = BT + (size_t)e * (size_t)N * (size_t)K;

  int tid = threadIdx.x, lane = tid & 63, w = tid >> 6;
  int wr = w >> 1, wc = w & 1;     // 2x2 wave grid, wave tile 64x64

  f32x4 acc[4][4];
#pragma unroll
  for (int mm = 0; mm < 4; mm++)
#pragma unroll
    for (int nn = 0; nn < 4; nn++) acc[mm][nn] = (f32x4){0.f, 0.f, 0.f, 0.f};

  // ---- staging: linear chunk idx = j*256 + w*64 + lane; row = idx>>3 ----
  // row = j*32 + urow, urow = w*8 + lane>>3 (0..31); chunk c = lane&7.
  // Source pre-swizzled: src chunk = c ^ (row&7) = c ^ (urow&7).
  int urow = (w << 3) + (lane >> 3);
  int sc = (lane & 7) ^ (urow & 7);
  const char *aP0, *aP1, *aP2, *aP3, *bP0, *bP1, *bP2, *bP3;
  {
    size_t kb = (size_t)k0 * 2 + (size_t)sc * 16;
    int c0 = v2c[row0 + 0 * 32 + urow];  if (c0 < 0) c0 = 0;
    int c1 = v2c[row0 + 1 * 32 + urow];  if (c1 < 0) c1 = 0;
    int c2 = v2c[row0 + 2 * 32 + urow];  if (c2 < 0) c2 = 0;
    int c3 = v2c[row0 + 3 * 32 + urow];  if (c3 < 0) c3 = 0;
    aP0 = (const char*)(A + (size_t)c0 * K) + kb;
    aP1 = (const char*)(A + (size_t)c1 * K) + kb;
    aP2 = (const char*)(A + (size_t)c2 * K) + kb;
    aP3 = (const char*)(A + (size_t)c3 * K) + kb;
    bP0 = (const char*)(Bp + (size_t)(n0 + 0 * 32 + urow) * K) + kb;
    bP1 = (const char*)(Bp + (size_t)(n0 + 1 * 32 + urow) * K) + kb;
    bP2 = (const char*)(Bp + (size_t)(n0 + 2 * 32 + urow) * K) + kb;
    bP3 = (const char*)(Bp + (size_t)(n0 + 3 * 32 + urow) * K) + kb;
  }

  // ---- fragment read addressing (swizzled) ----
  int fr = lane & 15, fq = lane >> 4;
  int frs = fr & 7;

  for (int kk = 0; kk < nk; ++kk) {
    size_t kbo = (size_t)kk * 128;      // 64 elems * 2 B
    if (kk) __syncthreads();            // prior tile's reads complete
    glds16(aP0 + kbo, (char*)As + 0 * 4096 + (w << 10));
    glds16(bP0 + kbo, (char*)Bs + 0 * 4096 + (w << 10));
    glds16(aP1 + kbo, (char*)As + 1 * 4096 + (w << 10));
    glds16(bP1 + kbo, (char*)Bs + 1 * 4096 + (w << 10));
    glds16(aP2 + kbo, (char*)As + 2 * 4096 + (w << 10));
    glds16(bP2 + kbo, (char*)Bs + 2 * 4096 + (w << 10));
    glds16(aP3 + kbo, (char*)As + 3 * 4096 + (w << 10));
    glds16(bP3 + kbo, (char*)Bs + 3 * 4096 + (w << 10));
    __syncthreads();                    // drains vmcnt(0): tile visible
#pragma unroll
    for (int ks = 0; ks < 2; ++ks) {
      short8 af[4], bf[4];
      int kc = (((ks << 2) + fq) ^ frs) << 3;
#pragma unroll
      for (int i = 0; i < 4; ++i)
        af[i] = *(const short8*)&As[((wr << 6) + i * 16 + fr) * 64 + kc];
#pragma unroll
      for (int i = 0; i < 4; ++i)
        bf[i] = *(const short8*)&Bs[((wc << 6) + i * 16 + fr) * 64 + kc];
#pragma unroll
      for (int mm = 0; mm < 4; ++mm)
#pragma unroll
        for (int nn = 0; nn < 4; ++nn)
          acc[mm][nn] = __builtin_amdgcn_mfma_f32_16x16x32_bf16(af[mm], bf[nn], acc[mm][nn], 0, 0, 0);
    }
  }

  // ---- epilogue ----
  const float* bp = bias + (size_t)e * N;
  int cb = n0 + (wc << 6);
  if (MODE == 0) {
#pragma unroll
    for (int mm = 0; mm < 4; mm++) {
#pragma unroll
      for (int j = 0; j < 4; j++) {
        int vr = row0 + (wr << 6) + mm * 16 + (fq << 2) + j;
        int cr = v2c[vr];
        if (cr < 0) continue;
        ushort* hp = h1 + (size_t)cr * N + cb;
#pragma unroll
        for (int nn = 0; nn < 4; nn++) {
          float v = acc[mm][nn][j] + bp[cb + nn * 16 + fr];
          hp[nn * 16 + fr] = f2bf(gelu_t(v));
        }
      }
    }
  } else {
    bool addb = (k0 == 0);
#pragma unroll
    for (int mm = 0; mm < 4; mm++) {
#pragma unroll
      for (int j = 0; j < 4; j++) {
        int vr = row0 + (wr << 6) + mm * 16 + (fq << 2) + j;
        int t2 = tok[vr];
        if (t2 < 0) continue;
        float wgt = wl[vr];
#pragma unroll
        for (int nn = 0; nn < 4; nn++) {
          int c = cb + nn * 16 + fr;
          float v = acc[mm][nn][j] + (addb ? bp[c] : 0.f);
          atomicAdd(&Out[(size_t)t2 * (size_t)N + c], wgt * v);
        }
      }
    }
  }
}

extern "C" void kernel_launch(void* const* d_in, const int* in_sizes, int n_in,
                              void* d_out, int out_size, void* d_ws, size_t ws_size,
                              hipStream_t stream) {
  (void)in_sizes; (void)n_in; (void)out_size; (void)ws_size;
  const float* x    = (const float*)d_in[0];
  const float* bbuf = (const float*)d_in[1];
  const float* Wr   = (const float*)d_in[2];
  const float* br   = (const float*)d_in[3];
  const float* W1   = (const float*)d_in[4];
  const float* b1   = (const float*)d_in[5];
  const float* W2   = (const float*)d_in[6];
  const float* b2   = (const float*)d_in[7];
  float* out = (float*)d_out;

  char* ws = (char*)d_ws;
  ushort* W1T = (ushort*)ws;                          // [E][F][H] bf16  64 MB
  ushort* W2T = (ushort*)(ws + 67108864);             // [E][H][F] bf16  64 MB
  ushort* Xg  = (ushort*)(ws + 134217728);            // [NCOMP][H] bf16 32 MB
  ushort* h1  = (ushort*)(ws + 167772160);            // [NCOMP][F] bf16 128 MB
  char* meta  = ws + 301989888;
  int*   cnt  = (int*)(meta);
  int*   off  = (int*)(meta + 64);
  int*   coff = (int*)(meta + 128);
  int*   cur  = (int*)(meta + 192);
  int*   te   = (int*)(meta + 256);                   // [NTOK*2]
  float* tw   = (float*)(meta + 65792);               // [NTOK*2]
  int*   tok  = (int*)(meta + 131328);                // [VCAP]
  float* wl   = (float*)(meta + 205056);              // [VCAP]
  int*   v2c  = (int*)(meta + 278784);                // [VCAP]
  int*   ctok = (int*)(meta + 352512);                // [NCOMP]

  k_init<<<VMBLK, 256, 0, stream>>>(cnt, cur, tok, wl, v2c);
  k_transcvt<<<dim3(F_ / 64, H_ / 64, E_), 256, 0, stream>>>(W1, W1T, H_, F_);
  k_transcvt<<<dim3(H_ / 64, F_ / 64, E_), 256, 0, stream>>>(W2, W2T, F_, H_);
  k_router<<<NTOK / 4, 256, 0, stream>>>(x, Wr, br, bbuf, cnt, te, tw);
  k_offsets<<<1, 64, 0, stream>>>(cnt, off, coff);
  k_build<<<NTOK / 256, 256, 0, stream>>>(te, tw, off, coff, cur, tok, wl, v2c, ctok);
  k_gather<<<NCOMP, 256, 0, stream>>>(x, ctok, Xg);
  k_zero<<<(NTOK * H_ / 4) / 256, 256, 0, stream>>>(out);
  // GEMM1: M=18432 virt (144 m-tiles), N=4096 (32 n-tiles of 128), K=1024.
  k_gemm<0><<<32 * MT, 256, 0, stream>>>(Xg, W1T, b1, h1, nullptr,
                                         off, v2c, nullptr, nullptr,
                                         H_, F_, 32);
  // GEMM2: N=1024 (8 n-tiles of 128) x split-K 2 -> ne=16; K=4096.
  k_gemm<1><<<16 * MT, 256, 0, stream>>>(h1, W2T, b2, nullptr, out,
                                         off, v2c, tok, wl,
                                         F_, H_, 16);
}